// Round 6
// baseline (8062.727 us; speedup 1.0000x reference)
//
#include <hip/hip_runtime.h>

typedef unsigned short u16;
typedef unsigned int   u32;

#define N_NODES 100000
#define NQ      128
#define DD      128
#define NE      131072
#define OO      256   // 2*D

__device__ __forceinline__ float lrelu(float x){ return x > 0.0f ? x : 0.01f * x; }
__device__ __forceinline__ u32 fenc(float f){ u32 u = __float_as_uint(f); return (u & 0x80000000u) ? ~u : (u | 0x80000000u); }
__device__ __forceinline__ float fdec(u32 e){ u32 u = (e & 0x80000000u) ? (e & 0x7FFFFFFFu) : ~e; return __uint_as_float(u); }

// ---------------- K0: per-query tables Qleft/Qright = qs@W[:,256:384]^T + qr@W[:,384:512]^T + b
__global__ __launch_bounds__(256) void qtable_kernel(
    const float* __restrict__ qsrc, const float* __restrict__ qrel,
    const float* __restrict__ Wl, const float* __restrict__ bl,
    const float* __restrict__ Wr, const float* __restrict__ br,
    float* __restrict__ Qlt, float* __restrict__ Qrt)
{
  int b = blockIdx.x; int side = b >> 7; int q = b & 127; int o = threadIdx.x;
  __shared__ float s[2*DD];
  if (threadIdx.x < DD) s[threadIdx.x] = qsrc[q*DD + threadIdx.x];
  else                  s[threadIdx.x] = qrel[q*DD + threadIdx.x - DD];
  __syncthreads();
  const float* W    = side ? Wr : Wl;
  const float* bias = side ? br : bl;
  float acc = bias[o];
  const float* wrow = W + (size_t)o*512 + 256;
  #pragma unroll 4
  for (int k = 0; k < 2*DD; ++k) acc += s[k] * wrow[k];
  (side ? Qrt : Qlt)[q*OO + o] = acc;
}

// ---------------- K1: simple edge bilinear -> logits (pure f32 VALU) -----------
#define EB 8   // edges per block
__global__ __launch_bounds__(256) void edge_simple_kernel(
    const float* __restrict__ node_rep, const float* __restrict__ rel_emb,
    const float* __restrict__ Wl, const float* __restrict__ Wr, const float* __restrict__ Wc,
    const float* __restrict__ bcb,
    const float* __restrict__ Qlt, const float* __restrict__ Qrt,
    const int* __restrict__ idx_i, const int* __restrict__ idx_j, const int* __restrict__ qidx,
    float* __restrict__ logits)
{
  __shared__ float Xj[EB][DD];
  __shared__ float Xi[EB][DD];
  __shared__ float Xr[EB][DD];
  __shared__ float RR[EB][OO];
  __shared__ float red[4][EB];
  __shared__ int qidS[EB];

  const int tid = threadIdx.x;
  const int e0 = blockIdx.x * EB;
  if (tid < EB) qidS[tid] = qidx[e0 + tid];

  for (int c = tid; c < EB*DD; c += 256){
    int r = c >> 7, k = c & 127;
    Xj[r][k] = node_rep[(size_t)idx_j[e0 + r]*DD + k];
    Xi[r][k] = node_rep[(size_t)idx_i[e0 + r]*DD + k];
    Xr[r][k] = rel_emb[(size_t)(e0 + r)*DD + k];
  }
  __syncthreads();

  const int o = tid;
  float accR[EB], accL[EB];
  #pragma unroll
  for (int r = 0; r < EB; ++r){
    accR[r] = Qrt[qidS[r]*OO + o];
    accL[r] = Qlt[qidS[r]*OO + o];
  }
  const float* wr = Wr + (size_t)o*512;
  const float* wl = Wl + (size_t)o*512;
  for (int k = 0; k < DD; ++k){
    float wr0 = wr[k], wr1 = wr[DD + k];
    float wl0 = wl[k], wl1 = wl[DD + k];
    #pragma unroll
    for (int r = 0; r < EB; ++r){
      accR[r] += Xj[r][k]*wr0 + Xr[r][k]*wr1;
      accL[r] += Xi[r][k]*wl0 + Xr[r][k]*wl1;
    }
  }
  float LLo[EB];
  #pragma unroll
  for (int r = 0; r < EB; ++r){
    RR[r][o] = lrelu(accR[r]);
    LLo[r]   = lrelu(accL[r]);
  }
  __syncthreads();

  float acc2[EB];
  #pragma unroll
  for (int r = 0; r < EB; ++r) acc2[r] = bcb[o];
  const float* wc = Wc + (size_t)o*OO;
  for (int k = 0; k < OO; ++k){
    float w = wc[k];
    #pragma unroll
    for (int r = 0; r < EB; ++r) acc2[r] += RR[r][k]*w;
  }

  const int lane = tid & 63, w = tid >> 6;
  #pragma unroll
  for (int r = 0; r < EB; ++r){
    float p = LLo[r] * acc2[r];
    p += __shfl_xor(p, 1);  p += __shfl_xor(p, 2);
    p += __shfl_xor(p, 4);  p += __shfl_xor(p, 8);
    p += __shfl_xor(p, 16); p += __shfl_xor(p, 32);
    if (lane == 0) red[w][r] = p;
  }
  __syncthreads();
  if (tid < EB)
    logits[e0 + tid] = red[0][tid] + red[1][tid] + red[2][tid] + red[3][tid];
}

// ---------------- K2: segment softmax over idx_i + query counts ----------------
__global__ void seg_max_count_kernel(const float* __restrict__ logits,
    const int* __restrict__ idx_i, const int* __restrict__ qidx,
    u32* __restrict__ segmax, int* __restrict__ qcount)
{
  int e = blockIdx.x*256 + threadIdx.x; if (e >= NE) return;
  atomicMax(segmax + idx_i[e], fenc(logits[e]));
  atomicAdd(qcount + qidx[e], 1);
}

__global__ void seg_exp_sum_kernel(const float* __restrict__ logits,
    const int* __restrict__ idx_i, const u32* __restrict__ segmax,
    float* __restrict__ ex, float* __restrict__ denom)
{
  int e = blockIdx.x*256 + threadIdx.x; if (e >= NE) return;
  int i = idx_i[e];
  float d = fminf(logits[e] - fdec(segmax[i]), 0.0f);
  float v = expf(d);
  ex[e] = v;
  atomicAdd(denom + i, v);
}

__global__ void attn_target_kernel(const float* __restrict__ ex,
    const float* __restrict__ denom, const int* __restrict__ idx_i,
    const float* __restrict__ visited, float* __restrict__ attn, float* __restrict__ target)
{
  int e = blockIdx.x*256 + threadIdx.x; if (e >= NE) return;
  int i = idx_i[e];
  float a = ex[e] / fmaxf(denom[i], 1e-30f);
  attn[e] = a;
  target[e] = a * visited[i];
}

// ---------------- K3/K4: counting sort by query group --------------------------
__global__ void scan_kernel(const int* __restrict__ qcount,
                            int* __restrict__ qstart, int* __restrict__ qcursor)
{
  if (blockIdx.x == 0 && threadIdx.x == 0){
    int acc = 0;
    for (int i = 0; i < NQ; ++i){ qstart[i] = acc; qcursor[i] = acc; acc += qcount[i]; }
  }
}

__global__ void bucket_fill_kernel(const int* __restrict__ qidx,
                                   int* __restrict__ qcursor, int* __restrict__ bucket)
{
  int e = blockIdx.x*256 + threadIdx.x; if (e >= NE) return;
  int p = atomicAdd(qcursor + qidx[e], 1);
  bucket[p] = e;
}

// ---------------- K5: exact per-group top-k (count-beats, lexsort-stable) ------
#define TOPK_CAP 2560
__global__ __launch_bounds__(1024) void topk_kernel(
    const int* __restrict__ qcount, const int* __restrict__ qstart,
    const int* __restrict__ bucket, const float* __restrict__ target,
    const int* __restrict__ maxe_p, int* __restrict__ keep)
{
  __shared__ float ss[TOPK_CAP];
  __shared__ int   se[TOPK_CAP];
  int q = blockIdx.x;
  int m = qcount[q], start = qstart[q];
  int maxe = *maxe_p;
  if (maxe <= 0 || maxe > (1 << 30)){
    float f = __int_as_float(maxe);
    if (f > 0.0f && f < 1.0e9f) maxe = (int)f;
  }
  int tid = threadIdx.x;
  if (m <= maxe){
    for (int i = tid; i < m; i += 1024) keep[bucket[start + i]] = 1;
    return;
  }
  if (m <= TOPK_CAP){
    for (int i = tid; i < m; i += 1024){
      int e = bucket[start + i]; ss[i] = target[e]; se[i] = e;
    }
    __syncthreads();
    for (int i = tid; i < m; i += 1024){
      float s = ss[i]; int eid = se[i]; int cnt = 0;
      for (int j = 0; j < m; ++j){
        float sj = ss[j]; int ej = se[j];
        cnt += (sj > s) || (sj == s && ej < eid);
      }
      keep[eid] = (cnt < maxe) ? 1 : 0;
    }
  } else {
    for (int i = tid; i < m; i += 1024){
      int eid = bucket[start + i]; float s = target[eid]; int cnt = 0;
      for (int j = 0; j < m; ++j){
        int ej = bucket[start + j]; float sj = target[ej];
        cnt += (sj > s) || (sj == s && ej < eid);
      }
      keep[eid] = (cnt < maxe) ? 1 : 0;
    }
  }
}

// ---------------- K5b: scatter kept target scores into upd ---------------------
__global__ void upd_scatter_kernel(const int* __restrict__ keep,
    const float* __restrict__ target, const int* __restrict__ idx_j,
    float* __restrict__ upd)
{
  int e = blockIdx.x*256 + threadIdx.x;
  if (e >= NE) return;
  if (!keep[e]) return;
  atomicAdd(upd + idx_j[e], target[e]);
}

// ---------------- K5c: scatter attn-weighted hi into agg chunk [c0,c1) ---------
__global__ __launch_bounds__(256) void agg_scatter_kernel(
    const int* __restrict__ keep, const float* __restrict__ attn,
    const int* __restrict__ idx_i, const int* __restrict__ idx_j,
    const float* __restrict__ node_rep, float* __restrict__ aggc,
    int c0, int c1)
{
  int wid = (blockIdx.x * 256 + threadIdx.x) >> 6;
  if (wid >= NE) return;
  int jj = idx_j[wid];
  if (jj < c0 || jj >= c1) return;
  if (!keep[wid]) return;                 // wave-uniform
  int lane = threadIdx.x & 63;
  int ii = idx_i[wid];
  float a = attn[wid];
  float h0 = node_rep[(size_t)ii*DD + lane];
  float h1 = node_rep[(size_t)ii*DD + 64 + lane];
  atomicAdd(aggc + (size_t)(jj - c0)*DD + lane,      a*h0);
  atomicAdd(aggc + (size_t)(jj - c0)*DD + 64 + lane, a*h1);
}

// ---------------- K6: out_rep = leaky((node_rep+agg) @ Wstep^T + bstep), f32 out
__global__ __launch_bounds__(128) void final_simple_kernel(
    const float* __restrict__ node_rep, const float* __restrict__ aggc,
    const float* __restrict__ Wstep, const float* __restrict__ bstep,
    float* __restrict__ out_rep, int c0)
{
  __shared__ float x[DD];
  int m = blockIdx.x + c0; int o = threadIdx.x;
  x[o] = node_rep[(size_t)m*DD + o] + aggc[(size_t)blockIdx.x*DD + o];
  __syncthreads();
  float acc = bstep[o];
  const float* wrow = Wstep + (size_t)o*DD;
  #pragma unroll 4
  for (int k = 0; k < DD; ++k) acc += x[k]*wrow[k];
  out_rep[(size_t)m*DD + o] = lrelu(acc);
}

// ---------------- K7: updated_node_score copy (f32 out) ------------------------
__global__ void score_out_kernel(const float* __restrict__ upd, float* __restrict__ out)
{
  int i = blockIdx.x*256 + threadIdx.x;
  if (i < N_NODES) out[i] = upd[i];
}

// ---------------- host ---------------------------------------------------------
extern "C" void kernel_launch(void* const* d_in, const int* in_sizes, int n_in,
                              void* d_out, int out_size, void* d_ws, size_t ws_size,
                              hipStream_t stream)
{
  const float* visited  = (const float*)d_in[0];
  const float* node_rep = (const float*)d_in[1];
  const float* qsrc     = (const float*)d_in[2];
  const float* qrel     = (const float*)d_in[3];
  const float* rel_emb  = (const float*)d_in[4];
  const float* Wl       = (const float*)d_in[5];
  const float* bl       = (const float*)d_in[6];
  const float* Wr       = (const float*)d_in[7];
  const float* br       = (const float*)d_in[8];
  const float* Wc       = (const float*)d_in[9];
  const float* bcb      = (const float*)d_in[10];
  const float* Wstep    = (const float*)d_in[11];
  const float* bstep    = (const float*)d_in[12];
  const int* qidx       = (const int*)d_in[13];
  const int* idx_i      = (const int*)d_in[14];
  const int* idx_j      = (const int*)d_in[15];
  const int* maxe       = (const int*)d_in[16];

  // ---- budget-aware workspace layout (never exceed ws_size) ----
  char* wp = (char*)d_ws;
  size_t used = 0;
  auto alloc = [&](size_t bytes)->char*{
    size_t pad = (bytes + 255) & ~(size_t)255;
    char* p = wp + used; used += pad; return p;
  };
  float* Qlt    = (float*)alloc((size_t)NQ*OO*4);
  float* Qrt    = (float*)alloc((size_t)NQ*OO*4);
  float* logits = (float*)alloc((size_t)NE*4);
  float* ex     = (float*)alloc((size_t)NE*4);
  float* attn   = (float*)alloc((size_t)NE*4);
  float* target = (float*)alloc((size_t)NE*4);
  u32*   segmax = (u32*)  alloc((size_t)N_NODES*4);
  float* denom  = (float*)alloc((size_t)N_NODES*4);
  float* upd    = (float*)alloc((size_t)N_NODES*4);
  int*   qcount = (int*)  alloc((size_t)NQ*4);
  int*   qstart = (int*)  alloc((size_t)NQ*4);
  int*   qcursor= (int*)  alloc((size_t)NQ*4);
  int*   bucket = (int*)  alloc((size_t)NE*4);
  int*   keep   = (int*)  alloc((size_t)NE*4);

  // agg gets whatever remains, processed in node-chunks
  size_t avail = (ws_size > used + 256) ? (ws_size - used - 256) : 0;
  long long cn = (long long)(avail / ((size_t)DD*4));
  if (cn > N_NODES) cn = N_NODES;
  if (cn < 2048) cn = 2048;
  int chunk_nodes = (int)cn;
  int nchunks = (N_NODES + chunk_nodes - 1) / chunk_nodes;
  float* agg = (float*)alloc((size_t)chunk_nodes*DD*4);

  float* out_score = (float*)d_out;               // f32 outputs (reference dtype)
  float* out_rep   = (float*)d_out + N_NODES;

  hipMemsetAsync(segmax, 0, (size_t)N_NODES*4, stream);  // 0 < fenc(any float)
  hipMemsetAsync(denom,  0, (size_t)N_NODES*4, stream);
  hipMemsetAsync(upd,    0, (size_t)N_NODES*4, stream);
  hipMemsetAsync(qcount, 0, (size_t)NQ*4,      stream);
  hipMemsetAsync(keep,   0, (size_t)NE*4,      stream);

  qtable_kernel<<<256, 256, 0, stream>>>(qsrc, qrel, Wl, bl, Wr, br, Qlt, Qrt);

  edge_simple_kernel<<<NE/EB, 256, 0, stream>>>(node_rep, rel_emb, Wl, Wr, Wc, bcb,
                                                Qlt, Qrt, idx_i, idx_j, qidx, logits);

  seg_max_count_kernel<<<NE/256, 256, 0, stream>>>(logits, idx_i, qidx, segmax, qcount);
  seg_exp_sum_kernel  <<<NE/256, 256, 0, stream>>>(logits, idx_i, segmax, ex, denom);
  attn_target_kernel  <<<NE/256, 256, 0, stream>>>(ex, denom, idx_i, visited, attn, target);

  scan_kernel<<<1, 64, 0, stream>>>(qcount, qstart, qcursor);
  bucket_fill_kernel<<<NE/256, 256, 0, stream>>>(qidx, qcursor, bucket);
  topk_kernel<<<NQ, 1024, 0, stream>>>(qcount, qstart, bucket, target, maxe, keep);

  upd_scatter_kernel<<<NE/256, 256, 0, stream>>>(keep, target, idx_j, upd);
  score_out_kernel<<<(N_NODES + 255)/256, 256, 0, stream>>>(upd, out_score);

  for (int c = 0; c < nchunks; ++c){
    int c0 = c * chunk_nodes;
    int c1 = c0 + chunk_nodes; if (c1 > N_NODES) c1 = N_NODES;
    hipMemsetAsync(agg, 0, (size_t)(c1 - c0)*DD*4, stream);
    agg_scatter_kernel<<<NE/4, 256, 0, stream>>>(keep, attn, idx_i, idx_j,
                                                 node_rep, agg, c0, c1);
    final_simple_kernel<<<c1 - c0, 128, 0, stream>>>(node_rep, agg, Wstep, bstep,
                                                     out_rep, c0);
  }
}

// Round 7
// 2112.475 us; speedup vs baseline: 3.8167x; 3.8167x over previous
//
#include <hip/hip_runtime.h>

typedef unsigned short u16;
typedef unsigned int   u32;
typedef __attribute__((ext_vector_type(8))) short short8;
typedef __attribute__((ext_vector_type(4))) short short4v;
typedef __attribute__((ext_vector_type(4))) float f32x4;

#define N_NODES 100000
#define NQ      128
#define DD      128
#define NE      131072
#define OO      256   // 2*D

__device__ __forceinline__ float b2f(u16 b){ u32 u = ((u32)b) << 16; return __uint_as_float(u); }
__device__ __forceinline__ u16 f2b(float f){ u32 u = __float_as_uint(f); u32 r = (u + 0x7FFFu + ((u >> 16) & 1u)) >> 16; return (u16)r; }
__device__ __forceinline__ float lrelu(float x){ return x > 0.0f ? x : 0.01f * x; }
__device__ __forceinline__ u32 fenc(float f){ u32 u = __float_as_uint(f); return (u & 0x80000000u) ? ~u : (u | 0x80000000u); }
__device__ __forceinline__ float fdec(u32 e){ u32 u = (e & 0x80000000u) ? (e & 0x7FFFFFFFu) : ~e; return __uint_as_float(u); }

__device__ __forceinline__ void cvt8(const float* p, short8& ah, short8& al){
  f32x4 a0 = *(const f32x4*)p;
  f32x4 a1 = *(const f32x4*)(p + 4);
  #pragma unroll
  for (int i = 0; i < 4; ++i){
    u16 h = f2b(a0[i]); ah[i] = (short)h; al[i] = (short)f2b(a0[i] - b2f(h));
  }
  #pragma unroll
  for (int i = 0; i < 4; ++i){
    u16 h = f2b(a1[i]); ah[4+i] = (short)h; al[4+i] = (short)f2b(a1[i] - b2f(h));
  }
}

// ---------------- W split: f32 -> bf16 hi/lo ----------------------------------
__global__ void split_kernel(const float* __restrict__ src, u16* __restrict__ hi,
                             u16* __restrict__ lo, int n)
{
  int i = blockIdx.x*256 + threadIdx.x; if (i >= n) return;
  float x = src[i];
  u16 h = f2b(x);
  hi[i] = h;
  lo[i] = f2b(x - b2f(h));
}

// ---------------- K0: per-query tables (exact f32) ----------------------------
__global__ __launch_bounds__(256) void qtable_kernel(
    const float* __restrict__ qsrc, const float* __restrict__ qrel,
    const float* __restrict__ Wl, const float* __restrict__ bl,
    const float* __restrict__ Wr, const float* __restrict__ br,
    float* __restrict__ Qlt, float* __restrict__ Qrt)
{
  int b = blockIdx.x; int side = b >> 7; int q = b & 127; int o = threadIdx.x;
  __shared__ float s[2*DD];
  if (threadIdx.x < DD) s[threadIdx.x] = qsrc[q*DD + threadIdx.x];
  else                  s[threadIdx.x] = qrel[q*DD + threadIdx.x - DD];
  __syncthreads();
  const float* W    = side ? Wr : Wl;
  const float* bias = side ? br : bl;
  float acc = bias[o];
  const float* wrow = W + (size_t)o*512 + 256;
  #pragma unroll 4
  for (int k = 0; k < 2*DD; ++k) acc += s[k] * wrow[k];
  (side ? Qrt : Qlt)[q*OO + o] = acc;
}

// ---------------- K1: fused edge bilinear -> logits (hi/lo 3-term MFMA) -------
#define BM   32
#define RST  264
#define HST  136

__global__ __launch_bounds__(256) void edge_logits_kernel(
    const float* __restrict__ node_rep, const float* __restrict__ rel_emb,
    const u16* __restrict__ WlH, const u16* __restrict__ WlL,
    const u16* __restrict__ WrH, const u16* __restrict__ WrL,
    const u16* __restrict__ WcH, const u16* __restrict__ WcL,
    const float* __restrict__ bcb,
    const float* __restrict__ Qlt, const float* __restrict__ Qrt,
    const int* __restrict__ idx_i, const int* __restrict__ idx_j, const int* __restrict__ qidx,
    float* __restrict__ logits)
{
  __shared__ __align__(16) u16 HjHi[BM*HST];
  __shared__ __align__(16) u16 HjLo[BM*HST];
  __shared__ __align__(16) u16 RRhi[BM*RST];
  __shared__ __align__(16) u16 RRlo[BM*RST];
  __shared__ int qidS[BM];
  __shared__ float lpart[4][BM];

  const int tid = threadIdx.x;
  const int e0 = blockIdx.x * BM;
  const int lane = tid & 63, w = tid >> 6;
  const int ln = lane & 15, qd = lane >> 4;
  const int ow = w * 64;

  if (tid < BM) qidS[tid] = qidx[e0 + tid];

  // stage Hj: gather f32 rows, split to bf16 hi/lo in LDS
  for (int c = tid; c < BM*32; c += 256){
    int r = c >> 5, seg = (c & 31) << 2;
    int j = idx_j[e0 + r];
    f32x4 v = *(const f32x4*)(node_rep + (size_t)j*DD + seg);
    short4v h4, l4;
    #pragma unroll
    for (int i = 0; i < 4; ++i){
      u16 h = f2b(v[i]); h4[i] = (short)h; l4[i] = (short)f2b(v[i] - b2f(h));
    }
    *(short4v*)&HjHi[r*HST + seg] = h4;
    *(short4v*)&HjLo[r*HST + seg] = l4;
  }
  __syncthreads();

  // ---- right GEMM: acc = [Hj|Rel] @ Wr[:, 0:256]^T (3-term hi/lo) ----
  f32x4 acc[2][4];
  #pragma unroll
  for (int mt = 0; mt < 2; ++mt)
    #pragma unroll
    for (int nt = 0; nt < 4; ++nt) acc[mt][nt] = (f32x4){0.f,0.f,0.f,0.f};

  #pragma unroll
  for (int c = 0; c < 8; ++c){
    short8 bh[4], bl[4], ah[2], al[2];
    #pragma unroll
    for (int nt = 0; nt < 4; ++nt){
      int o = ow + nt*16 + ln;
      bh[nt] = *(const short8*)(WrH + (size_t)o*512 + c*32 + qd*8);
      bl[nt] = *(const short8*)(WrL + (size_t)o*512 + c*32 + qd*8);
    }
    if (c < 4){
      #pragma unroll
      for (int mt = 0; mt < 2; ++mt){
        int base = (mt*16 + ln)*HST + c*32 + qd*8;
        ah[mt] = *(const short8*)&HjHi[base];
        al[mt] = *(const short8*)&HjLo[base];
      }
    } else {
      #pragma unroll
      for (int mt = 0; mt < 2; ++mt)
        cvt8(rel_emb + (size_t)(e0 + mt*16 + ln)*DD + (c-4)*32 + qd*8, ah[mt], al[mt]);
    }
    #pragma unroll
    for (int mt = 0; mt < 2; ++mt)
      #pragma unroll
      for (int nt = 0; nt < 4; ++nt){
        acc[mt][nt] = __builtin_amdgcn_mfma_f32_16x16x32_bf16(ah[mt], bh[nt], acc[mt][nt], 0, 0, 0);
        acc[mt][nt] = __builtin_amdgcn_mfma_f32_16x16x32_bf16(ah[mt], bl[nt], acc[mt][nt], 0, 0, 0);
        acc[mt][nt] = __builtin_amdgcn_mfma_f32_16x16x32_bf16(al[mt], bh[nt], acc[mt][nt], 0, 0, 0);
      }
  }

  // epilogue: RR = leaky(acc + Qright[qid][col]); split into hi/lo in LDS
  #pragma unroll
  for (int mt = 0; mt < 2; ++mt)
    #pragma unroll
    for (int nt = 0; nt < 4; ++nt){
      int col = ow + nt*16 + ln;
      #pragma unroll
      for (int rg = 0; rg < 4; ++rg){
        int row = mt*16 + qd*4 + rg;
        float v = acc[mt][nt][rg] + Qrt[qidS[row]*OO + col];
        v = lrelu(v);
        u16 hi = f2b(v);
        RRhi[row*RST + col] = hi;
        RRlo[row*RST + col] = f2b(v - b2f(hi));
      }
    }
  __syncthreads();   // RR complete; all waves done reading Hj

  // re-stage Hi (idx_i rows)
  for (int c = tid; c < BM*32; c += 256){
    int r = c >> 5, seg = (c & 31) << 2;
    int ii = idx_i[e0 + r];
    f32x4 v = *(const f32x4*)(node_rep + (size_t)ii*DD + seg);
    short4v h4, l4;
    #pragma unroll
    for (int i = 0; i < 4; ++i){
      u16 h = f2b(v[i]); h4[i] = (short)h; l4[i] = (short)f2b(v[i] - b2f(h));
    }
    *(short4v*)&HjHi[r*HST + seg] = h4;
    *(short4v*)&HjLo[r*HST + seg] = l4;
  }
  __syncthreads();

  // ---- center GEMM: racc = (RRhi+RRlo) @ Wc^T (3-term) ----
  f32x4 racc[2][4];
  #pragma unroll
  for (int mt = 0; mt < 2; ++mt)
    #pragma unroll
    for (int nt = 0; nt < 4; ++nt) racc[mt][nt] = (f32x4){0.f,0.f,0.f,0.f};

  #pragma unroll
  for (int c = 0; c < 8; ++c){
    short8 bh[4], bl[4], ah[2], al[2];
    #pragma unroll
    for (int nt = 0; nt < 4; ++nt){
      int o = ow + nt*16 + ln;
      bh[nt] = *(const short8*)(WcH + (size_t)o*256 + c*32 + qd*8);
      bl[nt] = *(const short8*)(WcL + (size_t)o*256 + c*32 + qd*8);
    }
    #pragma unroll
    for (int mt = 0; mt < 2; ++mt){
      int base = (mt*16 + ln)*RST + c*32 + qd*8;
      ah[mt] = *(const short8*)&RRhi[base];
      al[mt] = *(const short8*)&RRlo[base];
    }
    #pragma unroll
    for (int mt = 0; mt < 2; ++mt)
      #pragma unroll
      for (int nt = 0; nt < 4; ++nt){
        racc[mt][nt] = __builtin_amdgcn_mfma_f32_16x16x32_bf16(ah[mt], bh[nt], racc[mt][nt], 0, 0, 0);
        racc[mt][nt] = __builtin_amdgcn_mfma_f32_16x16x32_bf16(ah[mt], bl[nt], racc[mt][nt], 0, 0, 0);
        racc[mt][nt] = __builtin_amdgcn_mfma_f32_16x16x32_bf16(al[mt], bh[nt], racc[mt][nt], 0, 0, 0);
      }
  }

  // ---- left GEMM: lacc = [Hi|Rel] @ Wl[:, 0:256]^T (3-term) ----
  f32x4 lacc[2][4];
  #pragma unroll
  for (int mt = 0; mt < 2; ++mt)
    #pragma unroll
    for (int nt = 0; nt < 4; ++nt) lacc[mt][nt] = (f32x4){0.f,0.f,0.f,0.f};

  #pragma unroll
  for (int c = 0; c < 8; ++c){
    short8 bh[4], bl[4], ah[2], al[2];
    #pragma unroll
    for (int nt = 0; nt < 4; ++nt){
      int o = ow + nt*16 + ln;
      bh[nt] = *(const short8*)(WlH + (size_t)o*512 + c*32 + qd*8);
      bl[nt] = *(const short8*)(WlL + (size_t)o*512 + c*32 + qd*8);
    }
    if (c < 4){
      #pragma unroll
      for (int mt = 0; mt < 2; ++mt){
        int base = (mt*16 + ln)*HST + c*32 + qd*8;
        ah[mt] = *(const short8*)&HjHi[base];
        al[mt] = *(const short8*)&HjLo[base];
      }
    } else {
      #pragma unroll
      for (int mt = 0; mt < 2; ++mt)
        cvt8(rel_emb + (size_t)(e0 + mt*16 + ln)*DD + (c-4)*32 + qd*8, ah[mt], al[mt]);
    }
    #pragma unroll
    for (int mt = 0; mt < 2; ++mt)
      #pragma unroll
      for (int nt = 0; nt < 4; ++nt){
        lacc[mt][nt] = __builtin_amdgcn_mfma_f32_16x16x32_bf16(ah[mt], bh[nt], lacc[mt][nt], 0, 0, 0);
        lacc[mt][nt] = __builtin_amdgcn_mfma_f32_16x16x32_bf16(ah[mt], bl[nt], lacc[mt][nt], 0, 0, 0);
        lacc[mt][nt] = __builtin_amdgcn_mfma_f32_16x16x32_bf16(al[mt], bh[nt], lacc[mt][nt], 0, 0, 0);
      }
  }

  // fused logits dot: sum_o leaky(L) * (R + b_center)
  float bcv[4];
  #pragma unroll
  for (int nt = 0; nt < 4; ++nt) bcv[nt] = bcb[ow + nt*16 + ln];

  float part[2][4];
  #pragma unroll
  for (int mt = 0; mt < 2; ++mt)
    #pragma unroll
    for (int rg = 0; rg < 4; ++rg) part[mt][rg] = 0.f;

  #pragma unroll
  for (int mt = 0; mt < 2; ++mt)
    #pragma unroll
    for (int nt = 0; nt < 4; ++nt){
      int col = ow + nt*16 + ln;
      #pragma unroll
      for (int rg = 0; rg < 4; ++rg){
        int row = mt*16 + qd*4 + rg;
        float lv = lacc[mt][nt][rg] + Qlt[qidS[row]*OO + col];
        lv = lrelu(lv);
        float rv = racc[mt][nt][rg] + bcv[nt];
        part[mt][rg] += lv * rv;
      }
    }

  #pragma unroll
  for (int mt = 0; mt < 2; ++mt)
    #pragma unroll
    for (int rg = 0; rg < 4; ++rg){
      float p = part[mt][rg];
      p += __shfl_xor(p, 1); p += __shfl_xor(p, 2);
      p += __shfl_xor(p, 4); p += __shfl_xor(p, 8);
      if (ln == 0) lpart[w][mt*16 + qd*4 + rg] = p;
    }
  __syncthreads();
  if (tid < BM)
    logits[e0 + tid] = lpart[0][tid] + lpart[1][tid] + lpart[2][tid] + lpart[3][tid];
}

// ---------------- K2: segment softmax over idx_i + query counts ----------------
__global__ void seg_max_count_kernel(const float* __restrict__ logits,
    const int* __restrict__ idx_i, const int* __restrict__ qidx,
    u32* __restrict__ segmax, int* __restrict__ qcount)
{
  int e = blockIdx.x*256 + threadIdx.x; if (e >= NE) return;
  atomicMax(segmax + idx_i[e], fenc(logits[e]));
  atomicAdd(qcount + qidx[e], 1);
}

__global__ void seg_exp_sum_kernel(const float* __restrict__ logits,
    const int* __restrict__ idx_i, const u32* __restrict__ segmax,
    float* __restrict__ ex, float* __restrict__ denom)
{
  int e = blockIdx.x*256 + threadIdx.x; if (e >= NE) return;
  int i = idx_i[e];
  float d = fminf(logits[e] - fdec(segmax[i]), 0.0f);
  float v = expf(d);
  ex[e] = v;
  atomicAdd(denom + i, v);
}

__global__ void attn_target_kernel(const float* __restrict__ ex,
    const float* __restrict__ denom, const int* __restrict__ idx_i,
    const float* __restrict__ visited, float* __restrict__ attn, float* __restrict__ target)
{
  int e = blockIdx.x*256 + threadIdx.x; if (e >= NE) return;
  int i = idx_i[e];
  float a = ex[e] / fmaxf(denom[i], 1e-30f);
  attn[e] = a;
  target[e] = a * visited[i];
}

// ---------------- K3/K4: counting sort by query group --------------------------
__global__ void scan_kernel(const int* __restrict__ qcount,
                            int* __restrict__ qstart, int* __restrict__ qcursor)
{
  if (blockIdx.x == 0 && threadIdx.x == 0){
    int acc = 0;
    for (int i = 0; i < NQ; ++i){ qstart[i] = acc; qcursor[i] = acc; acc += qcount[i]; }
  }
}

__global__ void bucket_fill_kernel(const int* __restrict__ qidx,
                                   int* __restrict__ qcursor, int* __restrict__ bucket)
{
  int e = blockIdx.x*256 + threadIdx.x; if (e >= NE) return;
  int p = atomicAdd(qcursor + qidx[e], 1);
  bucket[p] = e;
}

// ---------------- K5: exact per-group top-k (count-beats, lexsort-stable) ------
#define TOPK_CAP 2560
__global__ __launch_bounds__(1024) void topk_kernel(
    const int* __restrict__ qcount, const int* __restrict__ qstart,
    const int* __restrict__ bucket, const float* __restrict__ target,
    const int* __restrict__ maxe_p, int* __restrict__ keep)
{
  __shared__ float ss[TOPK_CAP];
  __shared__ int   se[TOPK_CAP];
  int q = blockIdx.x;
  int m = qcount[q], start = qstart[q];
  int maxe = *maxe_p;
  if (maxe <= 0 || maxe > (1 << 30)){
    float f = __int_as_float(maxe);
    if (f > 0.0f && f < 1.0e9f) maxe = (int)f;
  }
  int tid = threadIdx.x;
  if (m <= maxe){
    for (int i = tid; i < m; i += 1024) keep[bucket[start + i]] = 1;
    return;
  }
  if (m <= TOPK_CAP){
    for (int i = tid; i < m; i += 1024){
      int e = bucket[start + i]; ss[i] = target[e]; se[i] = e;
    }
    __syncthreads();
    for (int i = tid; i < m; i += 1024){
      float s = ss[i]; int eid = se[i]; int cnt = 0;
      for (int j = 0; j < m; ++j){
        float sj = ss[j]; int ej = se[j];
        cnt += (sj > s) || (sj == s && ej < eid);
      }
      keep[eid] = (cnt < maxe) ? 1 : 0;
    }
  } else {
    for (int i = tid; i < m; i += 1024){
      int eid = bucket[start + i]; float s = target[eid]; int cnt = 0;
      for (int j = 0; j < m; ++j){
        int ej = bucket[start + j]; float sj = target[ej];
        cnt += (sj > s) || (sj == s && ej < eid);
      }
      keep[eid] = (cnt < maxe) ? 1 : 0;
    }
  }
}

// ---------------- K5b: scatter kept target scores into upd ---------------------
__global__ void upd_scatter_kernel(const int* __restrict__ keep,
    const float* __restrict__ target, const int* __restrict__ idx_j,
    float* __restrict__ upd)
{
  int e = blockIdx.x*256 + threadIdx.x;
  if (e >= NE) return;
  if (!keep[e]) return;
  atomicAdd(upd + idx_j[e], target[e]);
}

// ---------------- K5c: scatter attn-weighted hi into agg chunk [c0,c1) ---------
__global__ __launch_bounds__(256) void agg_scatter_kernel(
    const int* __restrict__ keep, const float* __restrict__ attn,
    const int* __restrict__ idx_i, const int* __restrict__ idx_j,
    const float* __restrict__ node_rep, float* __restrict__ aggc,
    int c0, int c1)
{
  int wid = (blockIdx.x * 256 + threadIdx.x) >> 6;
  if (wid >= NE) return;
  int jj = idx_j[wid];
  if (jj < c0 || jj >= c1) return;
  if (!keep[wid]) return;                 // wave-uniform
  int lane = threadIdx.x & 63;
  int ii = idx_i[wid];
  float a = attn[wid];
  float h0 = node_rep[(size_t)ii*DD + lane];
  float h1 = node_rep[(size_t)ii*DD + 64 + lane];
  atomicAdd(aggc + (size_t)(jj - c0)*DD + lane,      a*h0);
  atomicAdd(aggc + (size_t)(jj - c0)*DD + 64 + lane, a*h1);
}

// ---------------- K6: out_rep = leaky((node_rep+agg) @ Wstep^T + bstep), f32 out
__global__ __launch_bounds__(128) void final_simple_kernel(
    const float* __restrict__ node_rep, const float* __restrict__ aggc,
    const float* __restrict__ Wstep, const float* __restrict__ bstep,
    float* __restrict__ out_rep, int c0)
{
  __shared__ float x[DD];
  int m = blockIdx.x + c0; int o = threadIdx.x;
  x[o] = node_rep[(size_t)m*DD + o] + aggc[(size_t)blockIdx.x*DD + o];
  __syncthreads();
  float acc = bstep[o];
  const float* wrow = Wstep + (size_t)o*DD;
  #pragma unroll 4
  for (int k = 0; k < DD; ++k) acc += x[k]*wrow[k];
  out_rep[(size_t)m*DD + o] = lrelu(acc);
}

// ---------------- K7: updated_node_score copy (f32 out) ------------------------
__global__ void score_out_kernel(const float* __restrict__ upd, float* __restrict__ out)
{
  int i = blockIdx.x*256 + threadIdx.x;
  if (i < N_NODES) out[i] = upd[i];
}

// ---------------- host ---------------------------------------------------------
extern "C" void kernel_launch(void* const* d_in, const int* in_sizes, int n_in,
                              void* d_out, int out_size, void* d_ws, size_t ws_size,
                              hipStream_t stream)
{
  const float* visited  = (const float*)d_in[0];
  const float* node_rep = (const float*)d_in[1];
  const float* qsrc     = (const float*)d_in[2];
  const float* qrel     = (const float*)d_in[3];
  const float* rel_emb  = (const float*)d_in[4];
  const float* Wl       = (const float*)d_in[5];
  const float* bl       = (const float*)d_in[6];
  const float* Wr       = (const float*)d_in[7];
  const float* br       = (const float*)d_in[8];
  const float* Wc       = (const float*)d_in[9];
  const float* bcb      = (const float*)d_in[10];
  const float* Wstep    = (const float*)d_in[11];
  const float* bstep    = (const float*)d_in[12];
  const int* qidx       = (const int*)d_in[13];
  const int* idx_i      = (const int*)d_in[14];
  const int* idx_j      = (const int*)d_in[15];
  const int* maxe       = (const int*)d_in[16];

  // ---- budget-aware workspace layout (never exceed ws_size) ----
  char* wp = (char*)d_ws;
  size_t used = 0;
  auto alloc = [&](size_t bytes)->char*{
    size_t pad = (bytes + 255) & ~(size_t)255;
    char* p = wp + used; used += pad; return p;
  };
  float* Qlt    = (float*)alloc((size_t)NQ*OO*4);
  float* Qrt    = (float*)alloc((size_t)NQ*OO*4);
  float* logits = (float*)alloc((size_t)NE*4);
  float* ex     = (float*)alloc((size_t)NE*4);
  float* attn   = (float*)alloc((size_t)NE*4);
  float* target = (float*)alloc((size_t)NE*4);
  u32*   segmax = (u32*)  alloc((size_t)N_NODES*4);
  float* denom  = (float*)alloc((size_t)N_NODES*4);
  float* upd    = (float*)alloc((size_t)N_NODES*4);
  int*   qcount = (int*)  alloc((size_t)NQ*4);
  int*   qstart = (int*)  alloc((size_t)NQ*4);
  int*   qcursor= (int*)  alloc((size_t)NQ*4);
  int*   bucket = (int*)  alloc((size_t)NE*4);
  int*   keep   = (int*)  alloc((size_t)NE*4);
  u16* WlH = (u16*)alloc((size_t)256*512*2); u16* WlL = (u16*)alloc((size_t)256*512*2);
  u16* WrH = (u16*)alloc((size_t)256*512*2); u16* WrL = (u16*)alloc((size_t)256*512*2);
  u16* WcH = (u16*)alloc((size_t)256*256*2); u16* WcL = (u16*)alloc((size_t)256*256*2);

  // agg gets whatever remains, processed in node-chunks
  size_t avail = (ws_size > used + 256) ? (ws_size - used - 256) : 0;
  long long cn = (long long)(avail / ((size_t)DD*4));
  if (cn > N_NODES) cn = N_NODES;
  if (cn < 2048) cn = 2048;
  int chunk_nodes = (int)cn;
  int nchunks = (N_NODES + chunk_nodes - 1) / chunk_nodes;
  float* agg = (float*)alloc((size_t)chunk_nodes*DD*4);

  float* out_score = (float*)d_out;               // f32 outputs (reference dtype)
  float* out_rep   = (float*)d_out + N_NODES;

  hipMemsetAsync(segmax, 0, (size_t)N_NODES*4, stream);  // 0 < fenc(any float)
  hipMemsetAsync(denom,  0, (size_t)N_NODES*4, stream);
  hipMemsetAsync(upd,    0, (size_t)N_NODES*4, stream);
  hipMemsetAsync(qcount, 0, (size_t)NQ*4,      stream);
  hipMemsetAsync(keep,   0, (size_t)NE*4,      stream);

  split_kernel<<<(256*512+255)/256, 256, 0, stream>>>(Wl, WlH, WlL, 256*512);
  split_kernel<<<(256*512+255)/256, 256, 0, stream>>>(Wr, WrH, WrL, 256*512);
  split_kernel<<<(256*256+255)/256, 256, 0, stream>>>(Wc, WcH, WcL, 256*256);

  qtable_kernel<<<256, 256, 0, stream>>>(qsrc, qrel, Wl, bl, Wr, br, Qlt, Qrt);

  edge_logits_kernel<<<NE/BM, 256, 0, stream>>>(node_rep, rel_emb,
      WlH, WlL, WrH, WrL, WcH, WcL, bcb, Qlt, Qrt, idx_i, idx_j, qidx, logits);

  seg_max_count_kernel<<<NE/256, 256, 0, stream>>>(logits, idx_i, qidx, segmax, qcount);
  seg_exp_sum_kernel  <<<NE/256, 256, 0, stream>>>(logits, idx_i, segmax, ex, denom);
  attn_target_kernel  <<<NE/256, 256, 0, stream>>>(ex, denom, idx_i, visited, attn, target);

  scan_kernel<<<1, 64, 0, stream>>>(qcount, qstart, qcursor);
  bucket_fill_kernel<<<NE/256, 256, 0, stream>>>(qidx, qcursor, bucket);
  topk_kernel<<<NQ, 1024, 0, stream>>>(qcount, qstart, bucket, target, maxe, keep);

  upd_scatter_kernel<<<NE/256, 256, 0, stream>>>(keep, target, idx_j, upd);
  score_out_kernel<<<(N_NODES + 255)/256, 256, 0, stream>>>(upd, out_score);

  for (int c = 0; c < nchunks; ++c){
    int c0 = c * chunk_nodes;
    int c1 = c0 + chunk_nodes; if (c1 > N_NODES) c1 = N_NODES;
    hipMemsetAsync(agg, 0, (size_t)(c1 - c0)*DD*4, stream);
    agg_scatter_kernel<<<NE/4, 256, 0, stream>>>(keep, attn, idx_i, idx_j,
                                                 node_rep, agg, c0, c1);
    final_simple_kernel<<<c1 - c0, 128, 0, stream>>>(node_rep, agg, Wstep, bstep,
                                                     out_rep, c0);
  }
}

// Round 8
// 1224.445 us; speedup vs baseline: 6.5848x; 1.7253x over previous
//
#include <hip/hip_runtime.h>

typedef unsigned short u16;
typedef unsigned int   u32;
typedef __attribute__((ext_vector_type(8))) short short8;
typedef __attribute__((ext_vector_type(4))) short short4v;
typedef __attribute__((ext_vector_type(4))) float f32x4;

#define N_NODES 100000
#define NQ      128
#define DD      128
#define NE      131072
#define OO      256   // 2*D

__device__ __forceinline__ float b2f(u16 b){ u32 u = ((u32)b) << 16; return __uint_as_float(u); }
__device__ __forceinline__ u16 f2b(float f){ u32 u = __float_as_uint(f); u32 r = (u + 0x7FFFu + ((u >> 16) & 1u)) >> 16; return (u16)r; }
__device__ __forceinline__ float lrelu(float x){ return x > 0.0f ? x : 0.01f * x; }
__device__ __forceinline__ u32 fenc(float f){ u32 u = __float_as_uint(f); return (u & 0x80000000u) ? ~u : (u | 0x80000000u); }
__device__ __forceinline__ float fdec(u32 e){ u32 u = (e & 0x80000000u) ? (e & 0x7FFFFFFFu) : ~e; return __uint_as_float(u); }

__device__ __forceinline__ void cvt8(const float* p, short8& ah, short8& al){
  f32x4 a0 = *(const f32x4*)p;
  f32x4 a1 = *(const f32x4*)(p + 4);
  #pragma unroll
  for (int i = 0; i < 4; ++i){
    u16 h = f2b(a0[i]); ah[i] = (short)h; al[i] = (short)f2b(a0[i] - b2f(h));
  }
  #pragma unroll
  for (int i = 0; i < 4; ++i){
    u16 h = f2b(a1[i]); ah[4+i] = (short)h; al[4+i] = (short)f2b(a1[i] - b2f(h));
  }
}

// ---------------- W split: f32 -> bf16 hi/lo ----------------------------------
__global__ void split_kernel(const float* __restrict__ src, u16* __restrict__ hi,
                             u16* __restrict__ lo, int n)
{
  int i = blockIdx.x*256 + threadIdx.x; if (i >= n) return;
  float x = src[i];
  u16 h = f2b(x);
  hi[i] = h;
  lo[i] = f2b(x - b2f(h));
}

// ---------------- K0: per-query tables (exact f32) ----------------------------
__global__ __launch_bounds__(256) void qtable_kernel(
    const float* __restrict__ qsrc, const float* __restrict__ qrel,
    const float* __restrict__ Wl, const float* __restrict__ bl,
    const float* __restrict__ Wr, const float* __restrict__ br,
    float* __restrict__ Qlt, float* __restrict__ Qrt)
{
  int b = blockIdx.x; int side = b >> 7; int q = b & 127; int o = threadIdx.x;
  __shared__ float s[2*DD];
  if (threadIdx.x < DD) s[threadIdx.x] = qsrc[q*DD + threadIdx.x];
  else                  s[threadIdx.x] = qrel[q*DD + threadIdx.x - DD];
  __syncthreads();
  const float* W    = side ? Wr : Wl;
  const float* bias = side ? br : bl;
  float acc = bias[o];
  const float* wrow = W + (size_t)o*512 + 256;
  #pragma unroll 4
  for (int k = 0; k < 2*DD; ++k) acc += s[k] * wrow[k];
  (side ? Qrt : Qlt)[q*OO + o] = acc;
}

// ---------------- K1: fused edge bilinear -> logits (hi/lo 3-term MFMA) -------
#define BM   32
#define RST  264
#define HST  136

__global__ __launch_bounds__(256) void edge_logits_kernel(
    const float* __restrict__ node_rep, const float* __restrict__ rel_emb,
    const u16* __restrict__ WlH, const u16* __restrict__ WlL,
    const u16* __restrict__ WrH, const u16* __restrict__ WrL,
    const u16* __restrict__ WcH, const u16* __restrict__ WcL,
    const float* __restrict__ bcb,
    const float* __restrict__ Qlt, const float* __restrict__ Qrt,
    const int* __restrict__ idx_i, const int* __restrict__ idx_j, const int* __restrict__ qidx,
    float* __restrict__ logits)
{
  __shared__ __align__(16) u16 HjHi[BM*HST];
  __shared__ __align__(16) u16 HjLo[BM*HST];
  __shared__ __align__(16) u16 RRhi[BM*RST];
  __shared__ __align__(16) u16 RRlo[BM*RST];
  __shared__ int qidS[BM];
  __shared__ float lpart[4][BM];

  const int tid = threadIdx.x;
  const int e0 = blockIdx.x * BM;
  const int lane = tid & 63, w = tid >> 6;
  const int ln = lane & 15, qd = lane >> 4;
  const int ow = w * 64;

  if (tid < BM) qidS[tid] = qidx[e0 + tid];

  for (int c = tid; c < BM*32; c += 256){
    int r = c >> 5, seg = (c & 31) << 2;
    int j = idx_j[e0 + r];
    f32x4 v = *(const f32x4*)(node_rep + (size_t)j*DD + seg);
    short4v h4, l4;
    #pragma unroll
    for (int i = 0; i < 4; ++i){
      u16 h = f2b(v[i]); h4[i] = (short)h; l4[i] = (short)f2b(v[i] - b2f(h));
    }
    *(short4v*)&HjHi[r*HST + seg] = h4;
    *(short4v*)&HjLo[r*HST + seg] = l4;
  }
  __syncthreads();

  f32x4 acc[2][4];
  #pragma unroll
  for (int mt = 0; mt < 2; ++mt)
    #pragma unroll
    for (int nt = 0; nt < 4; ++nt) acc[mt][nt] = (f32x4){0.f,0.f,0.f,0.f};

  #pragma unroll
  for (int c = 0; c < 8; ++c){
    short8 bh[4], bl[4], ah[2], al[2];
    #pragma unroll
    for (int nt = 0; nt < 4; ++nt){
      int o = ow + nt*16 + ln;
      bh[nt] = *(const short8*)(WrH + (size_t)o*512 + c*32 + qd*8);
      bl[nt] = *(const short8*)(WrL + (size_t)o*512 + c*32 + qd*8);
    }
    if (c < 4){
      #pragma unroll
      for (int mt = 0; mt < 2; ++mt){
        int base = (mt*16 + ln)*HST + c*32 + qd*8;
        ah[mt] = *(const short8*)&HjHi[base];
        al[mt] = *(const short8*)&HjLo[base];
      }
    } else {
      #pragma unroll
      for (int mt = 0; mt < 2; ++mt)
        cvt8(rel_emb + (size_t)(e0 + mt*16 + ln)*DD + (c-4)*32 + qd*8, ah[mt], al[mt]);
    }
    #pragma unroll
    for (int mt = 0; mt < 2; ++mt)
      #pragma unroll
      for (int nt = 0; nt < 4; ++nt){
        acc[mt][nt] = __builtin_amdgcn_mfma_f32_16x16x32_bf16(ah[mt], bh[nt], acc[mt][nt], 0, 0, 0);
        acc[mt][nt] = __builtin_amdgcn_mfma_f32_16x16x32_bf16(ah[mt], bl[nt], acc[mt][nt], 0, 0, 0);
        acc[mt][nt] = __builtin_amdgcn_mfma_f32_16x16x32_bf16(al[mt], bh[nt], acc[mt][nt], 0, 0, 0);
      }
  }

  #pragma unroll
  for (int mt = 0; mt < 2; ++mt)
    #pragma unroll
    for (int nt = 0; nt < 4; ++nt){
      int col = ow + nt*16 + ln;
      #pragma unroll
      for (int rg = 0; rg < 4; ++rg){
        int row = mt*16 + qd*4 + rg;
        float v = acc[mt][nt][rg] + Qrt[qidS[row]*OO + col];
        v = lrelu(v);
        u16 hi = f2b(v);
        RRhi[row*RST + col] = hi;
        RRlo[row*RST + col] = f2b(v - b2f(hi));
      }
    }
  __syncthreads();

  for (int c = tid; c < BM*32; c += 256){
    int r = c >> 5, seg = (c & 31) << 2;
    int ii = idx_i[e0 + r];
    f32x4 v = *(const f32x4*)(node_rep + (size_t)ii*DD + seg);
    short4v h4, l4;
    #pragma unroll
    for (int i = 0; i < 4; ++i){
      u16 h = f2b(v[i]); h4[i] = (short)h; l4[i] = (short)f2b(v[i] - b2f(h));
    }
    *(short4v*)&HjHi[r*HST + seg] = h4;
    *(short4v*)&HjLo[r*HST + seg] = l4;
  }
  __syncthreads();

  f32x4 racc[2][4];
  #pragma unroll
  for (int mt = 0; mt < 2; ++mt)
    #pragma unroll
    for (int nt = 0; nt < 4; ++nt) racc[mt][nt] = (f32x4){0.f,0.f,0.f,0.f};

  #pragma unroll
  for (int c = 0; c < 8; ++c){
    short8 bh[4], bl[4], ah[2], al[2];
    #pragma unroll
    for (int nt = 0; nt < 4; ++nt){
      int o = ow + nt*16 + ln;
      bh[nt] = *(const short8*)(WcH + (size_t)o*256 + c*32 + qd*8);
      bl[nt] = *(const short8*)(WcL + (size_t)o*256 + c*32 + qd*8);
    }
    #pragma unroll
    for (int mt = 0; mt < 2; ++mt){
      int base = (mt*16 + ln)*RST + c*32 + qd*8;
      ah[mt] = *(const short8*)&RRhi[base];
      al[mt] = *(const short8*)&RRlo[base];
    }
    #pragma unroll
    for (int mt = 0; mt < 2; ++mt)
      #pragma unroll
      for (int nt = 0; nt < 4; ++nt){
        racc[mt][nt] = __builtin_amdgcn_mfma_f32_16x16x32_bf16(ah[mt], bh[nt], racc[mt][nt], 0, 0, 0);
        racc[mt][nt] = __builtin_amdgcn_mfma_f32_16x16x32_bf16(ah[mt], bl[nt], racc[mt][nt], 0, 0, 0);
        racc[mt][nt] = __builtin_amdgcn_mfma_f32_16x16x32_bf16(al[mt], bh[nt], racc[mt][nt], 0, 0, 0);
      }
  }

  f32x4 lacc[2][4];
  #pragma unroll
  for (int mt = 0; mt < 2; ++mt)
    #pragma unroll
    for (int nt = 0; nt < 4; ++nt) lacc[mt][nt] = (f32x4){0.f,0.f,0.f,0.f};

  #pragma unroll
  for (int c = 0; c < 8; ++c){
    short8 bh[4], bl[4], ah[2], al[2];
    #pragma unroll
    for (int nt = 0; nt < 4; ++nt){
      int o = ow + nt*16 + ln;
      bh[nt] = *(const short8*)(WlH + (size_t)o*512 + c*32 + qd*8);
      bl[nt] = *(const short8*)(WlL + (size_t)o*512 + c*32 + qd*8);
    }
    if (c < 4){
      #pragma unroll
      for (int mt = 0; mt < 2; ++mt){
        int base = (mt*16 + ln)*HST + c*32 + qd*8;
        ah[mt] = *(const short8*)&HjHi[base];
        al[mt] = *(const short8*)&HjLo[base];
      }
    } else {
      #pragma unroll
      for (int mt = 0; mt < 2; ++mt)
        cvt8(rel_emb + (size_t)(e0 + mt*16 + ln)*DD + (c-4)*32 + qd*8, ah[mt], al[mt]);
    }
    #pragma unroll
    for (int mt = 0; mt < 2; ++mt)
      #pragma unroll
      for (int nt = 0; nt < 4; ++nt){
        lacc[mt][nt] = __builtin_amdgcn_mfma_f32_16x16x32_bf16(ah[mt], bh[nt], lacc[mt][nt], 0, 0, 0);
        lacc[mt][nt] = __builtin_amdgcn_mfma_f32_16x16x32_bf16(ah[mt], bl[nt], lacc[mt][nt], 0, 0, 0);
        lacc[mt][nt] = __builtin_amdgcn_mfma_f32_16x16x32_bf16(al[mt], bh[nt], lacc[mt][nt], 0, 0, 0);
      }
  }

  float bcv[4];
  #pragma unroll
  for (int nt = 0; nt < 4; ++nt) bcv[nt] = bcb[ow + nt*16 + ln];

  float part[2][4];
  #pragma unroll
  for (int mt = 0; mt < 2; ++mt)
    #pragma unroll
    for (int rg = 0; rg < 4; ++rg) part[mt][rg] = 0.f;

  #pragma unroll
  for (int mt = 0; mt < 2; ++mt)
    #pragma unroll
    for (int nt = 0; nt < 4; ++nt){
      int col = ow + nt*16 + ln;
      #pragma unroll
      for (int rg = 0; rg < 4; ++rg){
        int row = mt*16 + qd*4 + rg;
        float lv = lacc[mt][nt][rg] + Qlt[qidS[row]*OO + col];
        lv = lrelu(lv);
        float rv = racc[mt][nt][rg] + bcv[nt];
        part[mt][rg] += lv * rv;
      }
    }

  #pragma unroll
  for (int mt = 0; mt < 2; ++mt)
    #pragma unroll
    for (int rg = 0; rg < 4; ++rg){
      float p = part[mt][rg];
      p += __shfl_xor(p, 1); p += __shfl_xor(p, 2);
      p += __shfl_xor(p, 4); p += __shfl_xor(p, 8);
      if (ln == 0) lpart[w][mt*16 + qd*4 + rg] = p;
    }
  __syncthreads();
  if (tid < BM)
    logits[e0 + tid] = lpart[0][tid] + lpart[1][tid] + lpart[2][tid] + lpart[3][tid];
}

// ---------------- K2: segment softmax over idx_i + query counts ----------------
__global__ void seg_max_count_kernel(const float* __restrict__ logits,
    const int* __restrict__ idx_i, const int* __restrict__ qidx,
    u32* __restrict__ segmax, int* __restrict__ qcount)
{
  int e = blockIdx.x*256 + threadIdx.x; if (e >= NE) return;
  atomicMax(segmax + idx_i[e], fenc(logits[e]));
  atomicAdd(qcount + qidx[e], 1);
}

__global__ void seg_exp_sum_kernel(const float* __restrict__ logits,
    const int* __restrict__ idx_i, const u32* __restrict__ segmax,
    float* __restrict__ ex, float* __restrict__ denom)
{
  int e = blockIdx.x*256 + threadIdx.x; if (e >= NE) return;
  int i = idx_i[e];
  float d = fminf(logits[e] - fdec(segmax[i]), 0.0f);
  float v = expf(d);
  ex[e] = v;
  atomicAdd(denom + i, v);
}

__global__ void attn_target_kernel(const float* __restrict__ ex,
    const float* __restrict__ denom, const int* __restrict__ idx_i,
    const float* __restrict__ visited, float* __restrict__ attn, float* __restrict__ target)
{
  int e = blockIdx.x*256 + threadIdx.x; if (e >= NE) return;
  int i = idx_i[e];
  float a = ex[e] / fmaxf(denom[i], 1e-30f);
  attn[e] = a;
  target[e] = a * visited[i];
}

// ---------------- K3/K4: counting sort by query group --------------------------
__global__ void scan_kernel(const int* __restrict__ qcount,
                            int* __restrict__ qstart, int* __restrict__ qcursor)
{
  if (blockIdx.x == 0 && threadIdx.x == 0){
    int acc = 0;
    for (int i = 0; i < NQ; ++i){ qstart[i] = acc; qcursor[i] = acc; acc += qcount[i]; }
  }
}

__global__ void bucket_fill_kernel(const int* __restrict__ qidx,
                                   int* __restrict__ qcursor, int* __restrict__ bucket)
{
  int e = blockIdx.x*256 + threadIdx.x; if (e >= NE) return;
  int p = atomicAdd(qcursor + qidx[e], 1);
  bucket[p] = e;
}

// ---------------- K5: exact per-group top-k (count-beats, lexsort-stable) ------
#define TOPK_CAP 2560
__global__ __launch_bounds__(1024) void topk_kernel(
    const int* __restrict__ qcount, const int* __restrict__ qstart,
    const int* __restrict__ bucket, const float* __restrict__ target,
    const int* __restrict__ maxe_p, int* __restrict__ keep)
{
  __shared__ float ss[TOPK_CAP];
  __shared__ int   se[TOPK_CAP];
  int q = blockIdx.x;
  int m = qcount[q], start = qstart[q];
  int maxe = *maxe_p;
  if (maxe <= 0 || maxe > (1 << 30)){
    float f = __int_as_float(maxe);
    if (f > 0.0f && f < 1.0e9f) maxe = (int)f;
  }
  int tid = threadIdx.x;
  if (m <= maxe){
    for (int i = tid; i < m; i += 1024) keep[bucket[start + i]] = 1;
    return;
  }
  if (m <= TOPK_CAP){
    for (int i = tid; i < m; i += 1024){
      int e = bucket[start + i]; ss[i] = target[e]; se[i] = e;
    }
    __syncthreads();
    for (int i = tid; i < m; i += 1024){
      float s = ss[i]; int eid = se[i]; int cnt = 0;
      for (int j = 0; j < m; ++j){
        float sj = ss[j]; int ej = se[j];
        cnt += (sj > s) || (sj == s && ej < eid);
      }
      keep[eid] = (cnt < maxe) ? 1 : 0;
    }
  } else {
    for (int i = tid; i < m; i += 1024){
      int eid = bucket[start + i]; float s = target[eid]; int cnt = 0;
      for (int j = 0; j < m; ++j){
        int ej = bucket[start + j]; float sj = target[ej];
        cnt += (sj > s) || (sj == s && ej < eid);
      }
      keep[eid] = (cnt < maxe) ? 1 : 0;
    }
  }
}

// ---------------- K5b: scatter kept target scores into upd ---------------------
__global__ void upd_scatter_kernel(const int* __restrict__ keep,
    const float* __restrict__ target, const int* __restrict__ idx_j,
    float* __restrict__ upd)
{
  int e = blockIdx.x*256 + threadIdx.x;
  if (e >= NE) return;
  if (!keep[e]) return;
  atomicAdd(upd + idx_j[e], target[e]);
}

// ---------------- K5c: scatter attn-weighted hi into agg chunk [c0,c1) ---------
__global__ __launch_bounds__(256) void agg_scatter_kernel(
    const int* __restrict__ keep, const float* __restrict__ attn,
    const int* __restrict__ idx_i, const int* __restrict__ idx_j,
    const float* __restrict__ node_rep, float* __restrict__ aggc,
    int c0, int c1)
{
  int wid = (blockIdx.x * 256 + threadIdx.x) >> 6;
  if (wid >= NE) return;
  int jj = idx_j[wid];
  if (jj < c0 || jj >= c1) return;
  if (!keep[wid]) return;                 // wave-uniform
  int lane = threadIdx.x & 63;
  int ii = idx_i[wid];
  float a = attn[wid];
  float h0 = node_rep[(size_t)ii*DD + lane];
  float h1 = node_rep[(size_t)ii*DD + 64 + lane];
  atomicAdd(aggc + (size_t)(jj - c0)*DD + lane,      a*h0);
  atomicAdd(aggc + (size_t)(jj - c0)*DD + 64 + lane, a*h1);
}

// ---------------- K6: out_rep = leaky((node_rep+agg) @ Wstep^T + bstep), MFMA ---
__global__ __launch_bounds__(256) void final_mfma_kernel(
    const float* __restrict__ node_rep, const float* __restrict__ aggc,
    const u16* __restrict__ WsH, const u16* __restrict__ WsL,
    const float* __restrict__ bstep, float* __restrict__ out_rep,
    int c0, int c1)
{
  __shared__ __align__(16) u16 Ahi[64*HST];
  __shared__ __align__(16) u16 Alo[64*HST];
  const int tid = threadIdx.x;
  const int m0 = c0 + blockIdx.x * 64;

  // stage A = node_rep + agg, split to bf16 hi/lo in LDS
  for (int c = tid; c < 64*32; c += 256){
    int r = c >> 5, seg = (c & 31) << 2;
    int m = m0 + r;
    float v[4];
    if (m < c1){
      const float* nr = node_rep + (size_t)m*DD + seg;
      const float* ag = aggc + (size_t)(m - c0)*DD + seg;
      #pragma unroll
      for (int i = 0; i < 4; ++i) v[i] = nr[i] + ag[i];
    } else {
      #pragma unroll
      for (int i = 0; i < 4; ++i) v[i] = 0.f;
    }
    short4v h4, l4;
    #pragma unroll
    for (int i = 0; i < 4; ++i){
      u16 h = f2b(v[i]); h4[i] = (short)h; l4[i] = (short)f2b(v[i] - b2f(h));
    }
    *(short4v*)&Ahi[r*HST + seg] = h4;
    *(short4v*)&Alo[r*HST + seg] = l4;
  }
  __syncthreads();

  const int lane = tid & 63, w = tid >> 6;
  const int ln = lane & 15, qd = lane >> 4;
  const int ow = w * 32;

  short8 bh[2][4], bl[2][4];
  #pragma unroll
  for (int nt = 0; nt < 2; ++nt)
    #pragma unroll
    for (int c = 0; c < 4; ++c){
      int o = ow + nt*16 + ln;
      bh[nt][c] = *(const short8*)(WsH + (size_t)o*DD + c*32 + qd*8);
      bl[nt][c] = *(const short8*)(WsL + (size_t)o*DD + c*32 + qd*8);
    }

  f32x4 acc[4][2];
  #pragma unroll
  for (int mt = 0; mt < 4; ++mt)
    #pragma unroll
    for (int nt = 0; nt < 2; ++nt) acc[mt][nt] = (f32x4){0.f,0.f,0.f,0.f};

  #pragma unroll
  for (int mt = 0; mt < 4; ++mt)
    #pragma unroll
    for (int c = 0; c < 4; ++c){
      int base = (mt*16 + ln)*HST + c*32 + qd*8;
      short8 ah = *(const short8*)&Ahi[base];
      short8 al = *(const short8*)&Alo[base];
      #pragma unroll
      for (int nt = 0; nt < 2; ++nt){
        acc[mt][nt] = __builtin_amdgcn_mfma_f32_16x16x32_bf16(ah, bh[nt][c], acc[mt][nt], 0, 0, 0);
        acc[mt][nt] = __builtin_amdgcn_mfma_f32_16x16x32_bf16(ah, bl[nt][c], acc[mt][nt], 0, 0, 0);
        acc[mt][nt] = __builtin_amdgcn_mfma_f32_16x16x32_bf16(al, bh[nt][c], acc[mt][nt], 0, 0, 0);
      }
    }

  #pragma unroll
  for (int mt = 0; mt < 4; ++mt)
    #pragma unroll
    for (int nt = 0; nt < 2; ++nt){
      int col = ow + nt*16 + ln;
      float bs = bstep[col];
      #pragma unroll
      for (int rg = 0; rg < 4; ++rg){
        int m = m0 + mt*16 + qd*4 + rg;
        if (m < c1)
          out_rep[(size_t)m*DD + col] = lrelu(acc[mt][nt][rg] + bs);
      }
    }
}

// ---------------- K7: updated_node_score copy (f32 out) ------------------------
__global__ void score_out_kernel(const float* __restrict__ upd, float* __restrict__ out)
{
  int i = blockIdx.x*256 + threadIdx.x;
  if (i < N_NODES) out[i] = upd[i];
}

// ---------------- host ---------------------------------------------------------
extern "C" void kernel_launch(void* const* d_in, const int* in_sizes, int n_in,
                              void* d_out, int out_size, void* d_ws, size_t ws_size,
                              hipStream_t stream)
{
  const float* visited  = (const float*)d_in[0];
  const float* node_rep = (const float*)d_in[1];
  const float* qsrc     = (const float*)d_in[2];
  const float* qrel     = (const float*)d_in[3];
  const float* rel_emb  = (const float*)d_in[4];
  const float* Wl       = (const float*)d_in[5];
  const float* bl       = (const float*)d_in[6];
  const float* Wr       = (const float*)d_in[7];
  const float* br       = (const float*)d_in[8];
  const float* Wc       = (const float*)d_in[9];
  const float* bcb      = (const float*)d_in[10];
  const float* Wstep    = (const float*)d_in[11];
  const float* bstep    = (const float*)d_in[12];
  const int* qidx       = (const int*)d_in[13];
  const int* idx_i      = (const int*)d_in[14];
  const int* idx_j      = (const int*)d_in[15];
  const int* maxe       = (const int*)d_in[16];

  // ---- budget-aware workspace layout (never exceed ws_size) ----
  char* wp = (char*)d_ws;
  size_t used = 0;
  auto alloc = [&](size_t bytes)->char*{
    size_t pad = (bytes + 255) & ~(size_t)255;
    char* p = wp + used; used += pad; return p;
  };
  float* Qlt    = (float*)alloc((size_t)NQ*OO*4);
  float* Qrt    = (float*)alloc((size_t)NQ*OO*4);
  float* logits = (float*)alloc((size_t)NE*4);
  float* ex     = (float*)alloc((size_t)NE*4);
  float* attn   = (float*)alloc((size_t)NE*4);
  float* target = (float*)alloc((size_t)NE*4);
  u32*   segmax = (u32*)  alloc((size_t)N_NODES*4);
  float* denom  = (float*)alloc((size_t)N_NODES*4);
  float* upd    = (float*)alloc((size_t)N_NODES*4);
  int*   qcount = (int*)  alloc((size_t)NQ*4);
  int*   qstart = (int*)  alloc((size_t)NQ*4);
  int*   qcursor= (int*)  alloc((size_t)NQ*4);
  int*   bucket = (int*)  alloc((size_t)NE*4);
  int*   keep   = (int*)  alloc((size_t)NE*4);
  u16* WlH = (u16*)alloc((size_t)256*512*2); u16* WlL = (u16*)alloc((size_t)256*512*2);
  u16* WrH = (u16*)alloc((size_t)256*512*2); u16* WrL = (u16*)alloc((size_t)256*512*2);
  u16* WcH = (u16*)alloc((size_t)256*256*2); u16* WcL = (u16*)alloc((size_t)256*256*2);
  u16* WsH = (u16*)alloc((size_t)128*128*2); u16* WsL = (u16*)alloc((size_t)128*128*2);

  // agg gets whatever remains, processed in node-chunks
  size_t avail = (ws_size > used + 256) ? (ws_size - used - 256) : 0;
  long long cn = (long long)(avail / ((size_t)DD*4));
  if (cn > N_NODES) cn = N_NODES;
  if (cn < 2048) cn = 2048;
  int chunk_nodes = (int)cn;
  int nchunks = (N_NODES + chunk_nodes - 1) / chunk_nodes;
  float* agg = (float*)alloc((size_t)chunk_nodes*DD*4);

  float* out_score = (float*)d_out;               // f32 outputs
  float* out_rep   = (float*)d_out + N_NODES;

  hipMemsetAsync(segmax, 0, (size_t)N_NODES*4, stream);
  hipMemsetAsync(denom,  0, (size_t)N_NODES*4, stream);
  hipMemsetAsync(upd,    0, (size_t)N_NODES*4, stream);
  hipMemsetAsync(qcount, 0, (size_t)NQ*4,      stream);
  hipMemsetAsync(keep,   0, (size_t)NE*4,      stream);

  split_kernel<<<(256*512+255)/256, 256, 0, stream>>>(Wl, WlH, WlL, 256*512);
  split_kernel<<<(256*512+255)/256, 256, 0, stream>>>(Wr, WrH, WrL, 256*512);
  split_kernel<<<(256*256+255)/256, 256, 0, stream>>>(Wc, WcH, WcL, 256*256);
  split_kernel<<<(128*128+255)/256, 256, 0, stream>>>(Wstep, WsH, WsL, 128*128);

  qtable_kernel<<<256, 256, 0, stream>>>(qsrc, qrel, Wl, bl, Wr, br, Qlt, Qrt);

  edge_logits_kernel<<<NE/BM, 256, 0, stream>>>(node_rep, rel_emb,
      WlH, WlL, WrH, WrL, WcH, WcL, bcb, Qlt, Qrt, idx_i, idx_j, qidx, logits);

  seg_max_count_kernel<<<NE/256, 256, 0, stream>>>(logits, idx_i, qidx, segmax, qcount);
  seg_exp_sum_kernel  <<<NE/256, 256, 0, stream>>>(logits, idx_i, segmax, ex, denom);
  attn_target_kernel  <<<NE/256, 256, 0, stream>>>(ex, denom, idx_i, visited, attn, target);

  scan_kernel<<<1, 64, 0, stream>>>(qcount, qstart, qcursor);
  bucket_fill_kernel<<<NE/256, 256, 0, stream>>>(qidx, qcursor, bucket);
  topk_kernel<<<NQ, 1024, 0, stream>>>(qcount, qstart, bucket, target, maxe, keep);

  upd_scatter_kernel<<<NE/256, 256, 0, stream>>>(keep, target, idx_j, upd);
  score_out_kernel<<<(N_NODES + 255)/256, 256, 0, stream>>>(upd, out_score);

  for (int c = 0; c < nchunks; ++c){
    int c0 = c * chunk_nodes;
    int c1 = c0 + chunk_nodes; if (c1 > N_NODES) c1 = N_NODES;
    hipMemsetAsync(agg, 0, (size_t)(c1 - c0)*DD*4, stream);
    agg_scatter_kernel<<<NE/4, 256, 0, stream>>>(keep, attn, idx_i, idx_j,
                                                 node_rep, agg, c0, c1);
    final_mfma_kernel<<<(c1 - c0 + 63)/64, 256, 0, stream>>>(node_rep, agg,
                                                 WsH, WsL, bstep, out_rep, c0, c1);
  }
}

// Round 9
// 1149.044 us; speedup vs baseline: 7.0169x; 1.0656x over previous
//
#include <hip/hip_runtime.h>

typedef unsigned short u16;
typedef unsigned int   u32;
typedef __attribute__((ext_vector_type(8))) short short8;
typedef __attribute__((ext_vector_type(4))) short short4v;
typedef __attribute__((ext_vector_type(4))) float f32x4;

#define N_NODES 100000
#define NQ      128
#define DD      128
#define NE      131072
#define OO      256   // 2*D

__device__ __forceinline__ float b2f(u16 b){ u32 u = ((u32)b) << 16; return __uint_as_float(u); }
__device__ __forceinline__ u16 f2b(float f){ u32 u = __float_as_uint(f); u32 r = (u + 0x7FFFu + ((u >> 16) & 1u)) >> 16; return (u16)r; }
__device__ __forceinline__ float lrelu(float x){ return x > 0.0f ? x : 0.01f * x; }
__device__ __forceinline__ u32 fenc(float f){ u32 u = __float_as_uint(f); return (u & 0x80000000u) ? ~u : (u | 0x80000000u); }
__device__ __forceinline__ float fdec(u32 e){ u32 u = (e & 0x80000000u) ? (e & 0x7FFFFFFFu) : ~e; return __uint_as_float(u); }

__device__ __forceinline__ void cvt8(const float* p, short8& ah, short8& al){
  f32x4 a0 = *(const f32x4*)p;
  f32x4 a1 = *(const f32x4*)(p + 4);
  #pragma unroll
  for (int i = 0; i < 4; ++i){
    u16 h = f2b(a0[i]); ah[i] = (short)h; al[i] = (short)f2b(a0[i] - b2f(h));
  }
  #pragma unroll
  for (int i = 0; i < 4; ++i){
    u16 h = f2b(a1[i]); ah[4+i] = (short)h; al[4+i] = (short)f2b(a1[i] - b2f(h));
  }
}

// ---------------- W split: f32 -> bf16 hi/lo ----------------------------------
__global__ void split_kernel(const float* __restrict__ src, u16* __restrict__ hi,
                             u16* __restrict__ lo, int n)
{
  int i = blockIdx.x*256 + threadIdx.x; if (i >= n) return;
  float x = src[i];
  u16 h = f2b(x);
  hi[i] = h;
  lo[i] = f2b(x - b2f(h));
}

// ---------------- K0: per-query tables (exact f32) ----------------------------
__global__ __launch_bounds__(256) void qtable_kernel(
    const float* __restrict__ qsrc, const float* __restrict__ qrel,
    const float* __restrict__ Wl, const float* __restrict__ bl,
    const float* __restrict__ Wr, const float* __restrict__ br,
    float* __restrict__ Qlt, float* __restrict__ Qrt)
{
  int b = blockIdx.x; int side = b >> 7; int q = b & 127; int o = threadIdx.x;
  __shared__ float s[2*DD];
  if (threadIdx.x < DD) s[threadIdx.x] = qsrc[q*DD + threadIdx.x];
  else                  s[threadIdx.x] = qrel[q*DD + threadIdx.x - DD];
  __syncthreads();
  const float* W    = side ? Wr : Wl;
  const float* bias = side ? br : bl;
  float acc = bias[o];
  const float* wrow = W + (size_t)o*512 + 256;
  #pragma unroll 4
  for (int k = 0; k < 2*DD; ++k) acc += s[k] * wrow[k];
  (side ? Qrt : Qlt)[q*OO + o] = acc;
}

// ---------------- K1: fused edge bilinear -> logits (hi/lo 3-term MFMA) -------
// Register-double-buffered weight prefetch + Hi row pre-gather for MLP.
#define BM   32
#define RST  264
#define HST  136

__global__ __launch_bounds__(256, 3) void edge_logits_kernel(
    const float* __restrict__ node_rep, const float* __restrict__ rel_emb,
    const u16* __restrict__ WlH, const u16* __restrict__ WlL,
    const u16* __restrict__ WrH, const u16* __restrict__ WrL,
    const u16* __restrict__ WcH, const u16* __restrict__ WcL,
    const float* __restrict__ bcb,
    const float* __restrict__ Qlt, const float* __restrict__ Qrt,
    const int* __restrict__ idx_i, const int* __restrict__ idx_j, const int* __restrict__ qidx,
    float* __restrict__ logits)
{
  __shared__ __align__(16) u16 HjHi[BM*HST];
  __shared__ __align__(16) u16 HjLo[BM*HST];
  __shared__ __align__(16) u16 RRhi[BM*RST];
  __shared__ __align__(16) u16 RRlo[BM*RST];
  __shared__ int qidS[BM];
  __shared__ float lpart[4][BM];

  const int tid = threadIdx.x;
  const int e0 = blockIdx.x * BM;
  const int lane = tid & 63, w = tid >> 6;
  const int ln = lane & 15, qd = lane >> 4;
  const int ow = w * 64;

  if (tid < BM) qidS[tid] = qidx[e0 + tid];

  // stage Hj: gather f32 rows, split to bf16 hi/lo in LDS
  #pragma unroll
  for (int it = 0; it < 4; ++it){
    int c = tid + it*256;
    int r = c >> 5, seg = (c & 31) << 2;
    int j = idx_j[e0 + r];
    f32x4 v = *(const f32x4*)(node_rep + (size_t)j*DD + seg);
    short4v h4, l4;
    #pragma unroll
    for (int i = 0; i < 4; ++i){
      u16 h = f2b(v[i]); h4[i] = (short)h; l4[i] = (short)f2b(v[i] - b2f(h));
    }
    *(short4v*)&HjHi[r*HST + seg] = h4;
    *(short4v*)&HjLo[r*HST + seg] = l4;
  }

  // pre-gather Hi rows into registers (HBM latency hides under right GEMM)
  f32x4 hipre[4];
  #pragma unroll
  for (int it = 0; it < 4; ++it){
    int c = tid + it*256;
    int r = c >> 5, seg = (c & 31) << 2;
    int ii = idx_i[e0 + r];
    hipre[it] = *(const f32x4*)(node_rep + (size_t)ii*DD + seg);
  }
  __syncthreads();

  // ---- right GEMM: acc = [Hj|Rel] @ Wr[:, 0:256]^T (3-term hi/lo) ----
  f32x4 acc[2][4];
  #pragma unroll
  for (int mt = 0; mt < 2; ++mt)
    #pragma unroll
    for (int nt = 0; nt < 4; ++nt) acc[mt][nt] = (f32x4){0.f,0.f,0.f,0.f};

  {
    short8 nbh[4], nbl[4];
    #pragma unroll
    for (int nt = 0; nt < 4; ++nt){
      int o = ow + nt*16 + ln;
      nbh[nt] = *(const short8*)(WrH + (size_t)o*512 + qd*8);
      nbl[nt] = *(const short8*)(WrL + (size_t)o*512 + qd*8);
    }
    #pragma unroll
    for (int c = 0; c < 8; ++c){
      short8 bh[4], bl[4], ah[2], al[2];
      #pragma unroll
      for (int nt = 0; nt < 4; ++nt){ bh[nt] = nbh[nt]; bl[nt] = nbl[nt]; }
      if (c < 7){
        #pragma unroll
        for (int nt = 0; nt < 4; ++nt){
          int o = ow + nt*16 + ln;
          nbh[nt] = *(const short8*)(WrH + (size_t)o*512 + (c+1)*32 + qd*8);
          nbl[nt] = *(const short8*)(WrL + (size_t)o*512 + (c+1)*32 + qd*8);
        }
      }
      if (c < 4){
        #pragma unroll
        for (int mt = 0; mt < 2; ++mt){
          int base = (mt*16 + ln)*HST + c*32 + qd*8;
          ah[mt] = *(const short8*)&HjHi[base];
          al[mt] = *(const short8*)&HjLo[base];
        }
      } else {
        #pragma unroll
        for (int mt = 0; mt < 2; ++mt)
          cvt8(rel_emb + (size_t)(e0 + mt*16 + ln)*DD + (c-4)*32 + qd*8, ah[mt], al[mt]);
      }
      #pragma unroll
      for (int mt = 0; mt < 2; ++mt)
        #pragma unroll
        for (int nt = 0; nt < 4; ++nt){
          acc[mt][nt] = __builtin_amdgcn_mfma_f32_16x16x32_bf16(ah[mt], bh[nt], acc[mt][nt], 0, 0, 0);
          acc[mt][nt] = __builtin_amdgcn_mfma_f32_16x16x32_bf16(ah[mt], bl[nt], acc[mt][nt], 0, 0, 0);
          acc[mt][nt] = __builtin_amdgcn_mfma_f32_16x16x32_bf16(al[mt], bh[nt], acc[mt][nt], 0, 0, 0);
        }
    }
  }

  // epilogue: RR = leaky(acc + Qright[qid][col]); split into hi/lo in LDS
  #pragma unroll
  for (int mt = 0; mt < 2; ++mt)
    #pragma unroll
    for (int nt = 0; nt < 4; ++nt){
      int col = ow + nt*16 + ln;
      #pragma unroll
      for (int rg = 0; rg < 4; ++rg){
        int row = mt*16 + qd*4 + rg;
        float v = acc[mt][nt][rg] + Qrt[qidS[row]*OO + col];
        v = lrelu(v);
        u16 hi = f2b(v);
        RRhi[row*RST + col] = hi;
        RRlo[row*RST + col] = f2b(v - b2f(hi));
      }
    }
  __syncthreads();   // all waves done reading Hj; RR complete

  // restage Hi from pre-gathered registers (LDS writes only)
  #pragma unroll
  for (int it = 0; it < 4; ++it){
    int c = tid + it*256;
    int r = c >> 5, seg = (c & 31) << 2;
    f32x4 v = hipre[it];
    short4v h4, l4;
    #pragma unroll
    for (int i = 0; i < 4; ++i){
      u16 h = f2b(v[i]); h4[i] = (short)h; l4[i] = (short)f2b(v[i] - b2f(h));
    }
    *(short4v*)&HjHi[r*HST + seg] = h4;
    *(short4v*)&HjLo[r*HST + seg] = l4;
  }
  __syncthreads();

  // ---- center GEMM: racc = (RRhi+RRlo) @ Wc^T (3-term) ----
  f32x4 racc[2][4];
  #pragma unroll
  for (int mt = 0; mt < 2; ++mt)
    #pragma unroll
    for (int nt = 0; nt < 4; ++nt) racc[mt][nt] = (f32x4){0.f,0.f,0.f,0.f};

  {
    short8 nbh[4], nbl[4];
    #pragma unroll
    for (int nt = 0; nt < 4; ++nt){
      int o = ow + nt*16 + ln;
      nbh[nt] = *(const short8*)(WcH + (size_t)o*256 + qd*8);
      nbl[nt] = *(const short8*)(WcL + (size_t)o*256 + qd*8);
    }
    #pragma unroll
    for (int c = 0; c < 8; ++c){
      short8 bh[4], bl[4], ah[2], al[2];
      #pragma unroll
      for (int nt = 0; nt < 4; ++nt){ bh[nt] = nbh[nt]; bl[nt] = nbl[nt]; }
      if (c < 7){
        #pragma unroll
        for (int nt = 0; nt < 4; ++nt){
          int o = ow + nt*16 + ln;
          nbh[nt] = *(const short8*)(WcH + (size_t)o*256 + (c+1)*32 + qd*8);
          nbl[nt] = *(const short8*)(WcL + (size_t)o*256 + (c+1)*32 + qd*8);
        }
      }
      #pragma unroll
      for (int mt = 0; mt < 2; ++mt){
        int base = (mt*16 + ln)*RST + c*32 + qd*8;
        ah[mt] = *(const short8*)&RRhi[base];
        al[mt] = *(const short8*)&RRlo[base];
      }
      #pragma unroll
      for (int mt = 0; mt < 2; ++mt)
        #pragma unroll
        for (int nt = 0; nt < 4; ++nt){
          racc[mt][nt] = __builtin_amdgcn_mfma_f32_16x16x32_bf16(ah[mt], bh[nt], racc[mt][nt], 0, 0, 0);
          racc[mt][nt] = __builtin_amdgcn_mfma_f32_16x16x32_bf16(ah[mt], bl[nt], racc[mt][nt], 0, 0, 0);
          racc[mt][nt] = __builtin_amdgcn_mfma_f32_16x16x32_bf16(al[mt], bh[nt], racc[mt][nt], 0, 0, 0);
        }
    }
  }

  // ---- left GEMM: lacc = [Hi|Rel] @ Wl[:, 0:256]^T (3-term) ----
  f32x4 lacc[2][4];
  #pragma unroll
  for (int mt = 0; mt < 2; ++mt)
    #pragma unroll
    for (int nt = 0; nt < 4; ++nt) lacc[mt][nt] = (f32x4){0.f,0.f,0.f,0.f};

  {
    short8 nbh[4], nbl[4];
    #pragma unroll
    for (int nt = 0; nt < 4; ++nt){
      int o = ow + nt*16 + ln;
      nbh[nt] = *(const short8*)(WlH + (size_t)o*512 + qd*8);
      nbl[nt] = *(const short8*)(WlL + (size_t)o*512 + qd*8);
    }
    #pragma unroll
    for (int c = 0; c < 8; ++c){
      short8 bh[4], bl[4], ah[2], al[2];
      #pragma unroll
      for (int nt = 0; nt < 4; ++nt){ bh[nt] = nbh[nt]; bl[nt] = nbl[nt]; }
      if (c < 7){
        #pragma unroll
        for (int nt = 0; nt < 4; ++nt){
          int o = ow + nt*16 + ln;
          nbh[nt] = *(const short8*)(WlH + (size_t)o*512 + (c+1)*32 + qd*8);
          nbl[nt] = *(const short8*)(WlL + (size_t)o*512 + (c+1)*32 + qd*8);
        }
      }
      if (c < 4){
        #pragma unroll
        for (int mt = 0; mt < 2; ++mt){
          int base = (mt*16 + ln)*HST + c*32 + qd*8;
          ah[mt] = *(const short8*)&HjHi[base];
          al[mt] = *(const short8*)&HjLo[base];
        }
      } else {
        #pragma unroll
        for (int mt = 0; mt < 2; ++mt)
          cvt8(rel_emb + (size_t)(e0 + mt*16 + ln)*DD + (c-4)*32 + qd*8, ah[mt], al[mt]);
      }
      #pragma unroll
      for (int mt = 0; mt < 2; ++mt)
        #pragma unroll
        for (int nt = 0; nt < 4; ++nt){
          lacc[mt][nt] = __builtin_amdgcn_mfma_f32_16x16x32_bf16(ah[mt], bh[nt], lacc[mt][nt], 0, 0, 0);
          lacc[mt][nt] = __builtin_amdgcn_mfma_f32_16x16x32_bf16(ah[mt], bl[nt], lacc[mt][nt], 0, 0, 0);
          lacc[mt][nt] = __builtin_amdgcn_mfma_f32_16x16x32_bf16(al[mt], bh[nt], lacc[mt][nt], 0, 0, 0);
        }
    }
  }

  // fused logits dot: sum_o leaky(L) * (R + b_center)
  float bcv[4];
  #pragma unroll
  for (int nt = 0; nt < 4; ++nt) bcv[nt] = bcb[ow + nt*16 + ln];

  float part[2][4];
  #pragma unroll
  for (int mt = 0; mt < 2; ++mt)
    #pragma unroll
    for (int rg = 0; rg < 4; ++rg) part[mt][rg] = 0.f;

  #pragma unroll
  for (int mt = 0; mt < 2; ++mt)
    #pragma unroll
    for (int nt = 0; nt < 4; ++nt){
      int col = ow + nt*16 + ln;
      #pragma unroll
      for (int rg = 0; rg < 4; ++rg){
        int row = mt*16 + qd*4 + rg;
        float lv = lacc[mt][nt][rg] + Qlt[qidS[row]*OO + col];
        lv = lrelu(lv);
        float rv = racc[mt][nt][rg] + bcv[nt];
        part[mt][rg] += lv * rv;
      }
    }

  #pragma unroll
  for (int mt = 0; mt < 2; ++mt)
    #pragma unroll
    for (int rg = 0; rg < 4; ++rg){
      float p = part[mt][rg];
      p += __shfl_xor(p, 1); p += __shfl_xor(p, 2);
      p += __shfl_xor(p, 4); p += __shfl_xor(p, 8);
      if (ln == 0) lpart[w][mt*16 + qd*4 + rg] = p;
    }
  __syncthreads();
  if (tid < BM)
    logits[e0 + tid] = lpart[0][tid] + lpart[1][tid] + lpart[2][tid] + lpart[3][tid];
}

// ---------------- K2: segment softmax over idx_i + query counts ----------------
__global__ void seg_max_count_kernel(const float* __restrict__ logits,
    const int* __restrict__ idx_i, const int* __restrict__ qidx,
    u32* __restrict__ segmax, int* __restrict__ qcount)
{
  int e = blockIdx.x*256 + threadIdx.x; if (e >= NE) return;
  atomicMax(segmax + idx_i[e], fenc(logits[e]));
  atomicAdd(qcount + qidx[e], 1);
}

__global__ void seg_exp_sum_kernel(const float* __restrict__ logits,
    const int* __restrict__ idx_i, const u32* __restrict__ segmax,
    float* __restrict__ ex, float* __restrict__ denom)
{
  int e = blockIdx.x*256 + threadIdx.x; if (e >= NE) return;
  int i = idx_i[e];
  float d = fminf(logits[e] - fdec(segmax[i]), 0.0f);
  float v = expf(d);
  ex[e] = v;
  atomicAdd(denom + i, v);
}

__global__ void attn_target_kernel(const float* __restrict__ ex,
    const float* __restrict__ denom, const int* __restrict__ idx_i,
    const float* __restrict__ visited, float* __restrict__ attn, float* __restrict__ target)
{
  int e = blockIdx.x*256 + threadIdx.x; if (e >= NE) return;
  int i = idx_i[e];
  float a = ex[e] / fmaxf(denom[i], 1e-30f);
  attn[e] = a;
  target[e] = a * visited[i];
}

// ---------------- K3/K4: counting sort by query group --------------------------
__global__ void scan_kernel(const int* __restrict__ qcount,
                            int* __restrict__ qstart, int* __restrict__ qcursor)
{
  if (blockIdx.x == 0 && threadIdx.x == 0){
    int acc = 0;
    for (int i = 0; i < NQ; ++i){ qstart[i] = acc; qcursor[i] = acc; acc += qcount[i]; }
  }
}

__global__ void bucket_fill_kernel(const int* __restrict__ qidx,
                                   int* __restrict__ qcursor, int* __restrict__ bucket)
{
  int e = blockIdx.x*256 + threadIdx.x; if (e >= NE) return;
  int p = atomicAdd(qcursor + qidx[e], 1);
  bucket[p] = e;
}

// ---------------- K5: exact per-group top-k (count-beats, lexsort-stable) ------
#define TOPK_CAP 2560
__global__ __launch_bounds__(1024) void topk_kernel(
    const int* __restrict__ qcount, const int* __restrict__ qstart,
    const int* __restrict__ bucket, const float* __restrict__ target,
    const int* __restrict__ maxe_p, int* __restrict__ keep)
{
  __shared__ float ss[TOPK_CAP];
  __shared__ int   se[TOPK_CAP];
  int q = blockIdx.x;
  int m = qcount[q], start = qstart[q];
  int maxe = *maxe_p;
  if (maxe <= 0 || maxe > (1 << 30)){
    float f = __int_as_float(maxe);
    if (f > 0.0f && f < 1.0e9f) maxe = (int)f;
  }
  int tid = threadIdx.x;
  if (m <= maxe){
    for (int i = tid; i < m; i += 1024) keep[bucket[start + i]] = 1;
    return;
  }
  if (m <= TOPK_CAP){
    for (int i = tid; i < m; i += 1024){
      int e = bucket[start + i]; ss[i] = target[e]; se[i] = e;
    }
    __syncthreads();
    for (int i = tid; i < m; i += 1024){
      float s = ss[i]; int eid = se[i]; int cnt = 0;
      for (int j = 0; j < m; ++j){
        float sj = ss[j]; int ej = se[j];
        cnt += (sj > s) || (sj == s && ej < eid);
      }
      keep[eid] = (cnt < maxe) ? 1 : 0;
    }
  } else {
    for (int i = tid; i < m; i += 1024){
      int eid = bucket[start + i]; float s = target[eid]; int cnt = 0;
      for (int j = 0; j < m; ++j){
        int ej = bucket[start + j]; float sj = target[ej];
        cnt += (sj > s) || (sj == s && ej < eid);
      }
      keep[eid] = (cnt < maxe) ? 1 : 0;
    }
  }
}

// ---------------- K5b: scatter kept target scores into upd ---------------------
__global__ void upd_scatter_kernel(const int* __restrict__ keep,
    const float* __restrict__ target, const int* __restrict__ idx_j,
    float* __restrict__ upd)
{
  int e = blockIdx.x*256 + threadIdx.x;
  if (e >= NE) return;
  if (!keep[e]) return;
  atomicAdd(upd + idx_j[e], target[e]);
}

// ---------------- K5c: scatter attn-weighted hi into agg chunk [c0,c1) ---------
__global__ __launch_bounds__(256) void agg_scatter_kernel(
    const int* __restrict__ keep, const float* __restrict__ attn,
    const int* __restrict__ idx_i, const int* __restrict__ idx_j,
    const float* __restrict__ node_rep, float* __restrict__ aggc,
    int c0, int c1)
{
  int wid = (blockIdx.x * 256 + threadIdx.x) >> 6;
  if (wid >= NE) return;
  int jj = idx_j[wid];
  if (jj < c0 || jj >= c1) return;
  if (!keep[wid]) return;                 // wave-uniform
  int lane = threadIdx.x & 63;
  int ii = idx_i[wid];
  float a = attn[wid];
  float h0 = node_rep[(size_t)ii*DD + lane];
  float h1 = node_rep[(size_t)ii*DD + 64 + lane];
  atomicAdd(aggc + (size_t)(jj - c0)*DD + lane,      a*h0);
  atomicAdd(aggc + (size_t)(jj - c0)*DD + 64 + lane, a*h1);
}

// ---------------- K6: out_rep = leaky((node_rep+agg) @ Wstep^T + bstep), MFMA ---
__global__ __launch_bounds__(256) void final_mfma_kernel(
    const float* __restrict__ node_rep, const float* __restrict__ aggc,
    const u16* __restrict__ WsH, const u16* __restrict__ WsL,
    const float* __restrict__ bstep, float* __restrict__ out_rep,
    int c0, int c1)
{
  __shared__ __align__(16) u16 Ahi[64*HST];
  __shared__ __align__(16) u16 Alo[64*HST];
  const int tid = threadIdx.x;
  const int m0 = c0 + blockIdx.x * 64;

  for (int c = tid; c < 64*32; c += 256){
    int r = c >> 5, seg = (c & 31) << 2;
    int m = m0 + r;
    float v[4];
    if (m < c1){
      const float* nr = node_rep + (size_t)m*DD + seg;
      const float* ag = aggc + (size_t)(m - c0)*DD + seg;
      #pragma unroll
      for (int i = 0; i < 4; ++i) v[i] = nr[i] + ag[i];
    } else {
      #pragma unroll
      for (int i = 0; i < 4; ++i) v[i] = 0.f;
    }
    short4v h4, l4;
    #pragma unroll
    for (int i = 0; i < 4; ++i){
      u16 h = f2b(v[i]); h4[i] = (short)h; l4[i] = (short)f2b(v[i] - b2f(h));
    }
    *(short4v*)&Ahi[r*HST + seg] = h4;
    *(short4v*)&Alo[r*HST + seg] = l4;
  }
  __syncthreads();

  const int lane = tid & 63, w = tid >> 6;
  const int ln = lane & 15, qd = lane >> 4;
  const int ow = w * 32;

  short8 bh[2][4], bl[2][4];
  #pragma unroll
  for (int nt = 0; nt < 2; ++nt)
    #pragma unroll
    for (int c = 0; c < 4; ++c){
      int o = ow + nt*16 + ln;
      bh[nt][c] = *(const short8*)(WsH + (size_t)o*DD + c*32 + qd*8);
      bl[nt][c] = *(const short8*)(WsL + (size_t)o*DD + c*32 + qd*8);
    }

  f32x4 acc[4][2];
  #pragma unroll
  for (int mt = 0; mt < 4; ++mt)
    #pragma unroll
    for (int nt = 0; nt < 2; ++nt) acc[mt][nt] = (f32x4){0.f,0.f,0.f,0.f};

  #pragma unroll
  for (int mt = 0; mt < 4; ++mt)
    #pragma unroll
    for (int c = 0; c < 4; ++c){
      int base = (mt*16 + ln)*HST + c*32 + qd*8;
      short8 ah = *(const short8*)&Ahi[base];
      short8 al = *(const short8*)&Alo[base];
      #pragma unroll
      for (int nt = 0; nt < 2; ++nt){
        acc[mt][nt] = __builtin_amdgcn_mfma_f32_16x16x32_bf16(ah, bh[nt][c], acc[mt][nt], 0, 0, 0);
        acc[mt][nt] = __builtin_amdgcn_mfma_f32_16x16x32_bf16(ah, bl[nt][c], acc[mt][nt], 0, 0, 0);
        acc[mt][nt] = __builtin_amdgcn_mfma_f32_16x16x32_bf16(al, bh[nt][c], acc[mt][nt], 0, 0, 0);
      }
    }

  #pragma unroll
  for (int mt = 0; mt < 4; ++mt)
    #pragma unroll
    for (int nt = 0; nt < 2; ++nt){
      int col = ow + nt*16 + ln;
      float bs = bstep[col];
      #pragma unroll
      for (int rg = 0; rg < 4; ++rg){
        int m = m0 + mt*16 + qd*4 + rg;
        if (m < c1)
          out_rep[(size_t)m*DD + col] = lrelu(acc[mt][nt][rg] + bs);
      }
    }
}

// ---------------- K7: updated_node_score copy (f32 out) ------------------------
__global__ void score_out_kernel(const float* __restrict__ upd, float* __restrict__ out)
{
  int i = blockIdx.x*256 + threadIdx.x;
  if (i < N_NODES) out[i] = upd[i];
}

// ---------------- host ---------------------------------------------------------
extern "C" void kernel_launch(void* const* d_in, const int* in_sizes, int n_in,
                              void* d_out, int out_size, void* d_ws, size_t ws_size,
                              hipStream_t stream)
{
  const float* visited  = (const float*)d_in[0];
  const float* node_rep = (const float*)d_in[1];
  const float* qsrc     = (const float*)d_in[2];
  const float* qrel     = (const float*)d_in[3];
  const float* rel_emb  = (const float*)d_in[4];
  const float* Wl       = (const float*)d_in[5];
  const float* bl       = (const float*)d_in[6];
  const float* Wr       = (const float*)d_in[7];
  const float* br       = (const float*)d_in[8];
  const float* Wc       = (const float*)d_in[9];
  const float* bcb      = (const float*)d_in[10];
  const float* Wstep    = (const float*)d_in[11];
  const float* bstep    = (const float*)d_in[12];
  const int* qidx       = (const int*)d_in[13];
  const int* idx_i      = (const int*)d_in[14];
  const int* idx_j      = (const int*)d_in[15];
  const int* maxe       = (const int*)d_in[16];

  // ---- budget-aware workspace layout (never exceed ws_size) ----
  char* wp = (char*)d_ws;
  size_t used = 0;
  auto alloc = [&](size_t bytes)->char*{
    size_t pad = (bytes + 255) & ~(size_t)255;
    char* p = wp + used; used += pad; return p;
  };
  float* Qlt    = (float*)alloc((size_t)NQ*OO*4);
  float* Qrt    = (float*)alloc((size_t)NQ*OO*4);
  float* logits = (float*)alloc((size_t)NE*4);
  float* ex     = (float*)alloc((size_t)NE*4);
  float* attn   = (float*)alloc((size_t)NE*4);
  float* target = (float*)alloc((size_t)NE*4);
  u32*   segmax = (u32*)  alloc((size_t)N_NODES*4);
  float* denom  = (float*)alloc((size_t)N_NODES*4);
  float* upd    = (float*)alloc((size_t)N_NODES*4);
  int*   qcount = (int*)  alloc((size_t)NQ*4);
  int*   qstart = (int*)  alloc((size_t)NQ*4);
  int*   qcursor= (int*)  alloc((size_t)NQ*4);
  int*   bucket = (int*)  alloc((size_t)NE*4);
  int*   keep   = (int*)  alloc((size_t)NE*4);
  u16* WlH = (u16*)alloc((size_t)256*512*2); u16* WlL = (u16*)alloc((size_t)256*512*2);
  u16* WrH = (u16*)alloc((size_t)256*512*2); u16* WrL = (u16*)alloc((size_t)256*512*2);
  u16* WcH = (u16*)alloc((size_t)256*256*2); u16* WcL = (u16*)alloc((size_t)256*256*2);
  u16* WsH = (u16*)alloc((size_t)128*128*2); u16* WsL = (u16*)alloc((size_t)128*128*2);

  // agg gets whatever remains, processed in node-chunks
  size_t avail = (ws_size > used + 256) ? (ws_size - used - 256) : 0;
  long long cn = (long long)(avail / ((size_t)DD*4));
  if (cn > N_NODES) cn = N_NODES;
  if (cn < 2048) cn = 2048;
  int chunk_nodes = (int)cn;
  int nchunks = (N_NODES + chunk_nodes - 1) / chunk_nodes;
  float* agg = (float*)alloc((size_t)chunk_nodes*DD*4);

  float* out_score = (float*)d_out;               // f32 outputs
  float* out_rep   = (float*)d_out + N_NODES;

  hipMemsetAsync(segmax, 0, (size_t)N_NODES*4, stream);
  hipMemsetAsync(denom,  0, (size_t)N_NODES*4, stream);
  hipMemsetAsync(upd,    0, (size_t)N_NODES*4, stream);
  hipMemsetAsync(qcount, 0, (size_t)NQ*4,      stream);
  hipMemsetAsync(keep,   0, (size_t)NE*4,      stream);

  split_kernel<<<(256*512+255)/256, 256, 0, stream>>>(Wl, WlH, WlL, 256*512);
  split_kernel<<<(256*512+255)/256, 256, 0, stream>>>(Wr, WrH, WrL, 256*512);
  split_kernel<<<(256*256+255)/256, 256, 0, stream>>>(Wc, WcH, WcL, 256*256);
  split_kernel<<<(128*128+255)/256, 256, 0, stream>>>(Wstep, WsH, WsL, 128*128);

  qtable_kernel<<<256, 256, 0, stream>>>(qsrc, qrel, Wl, bl, Wr, br, Qlt, Qrt);

  edge_logits_kernel<<<NE/BM, 256, 0, stream>>>(node_rep, rel_emb,
      WlH, WlL, WrH, WrL, WcH, WcL, bcb, Qlt, Qrt, idx_i, idx_j, qidx, logits);

  seg_max_count_kernel<<<NE/256, 256, 0, stream>>>(logits, idx_i, qidx, segmax, qcount);
  seg_exp_sum_kernel  <<<NE/256, 256, 0, stream>>>(logits, idx_i, segmax, ex, denom);
  attn_target_kernel  <<<NE/256, 256, 0, stream>>>(ex, denom, idx_i, visited, attn, target);

  scan_kernel<<<1, 64, 0, stream>>>(qcount, qstart, qcursor);
  bucket_fill_kernel<<<NE/256, 256, 0, stream>>>(qidx, qcursor, bucket);
  topk_kernel<<<NQ, 1024, 0, stream>>>(qcount, qstart, bucket, target, maxe, keep);

  upd_scatter_kernel<<<NE/256, 256, 0, stream>>>(keep, target, idx_j, upd);
  score_out_kernel<<<(N_NODES + 255)/256, 256, 0, stream>>>(upd, out_score);

  for (int c = 0; c < nchunks; ++c){
    int c0 = c * chunk_nodes;
    int c1 = c0 + chunk_nodes; if (c1 > N_NODES) c1 = N_NODES;
    hipMemsetAsync(agg, 0, (size_t)(c1 - c0)*DD*4, stream);
    agg_scatter_kernel<<<NE/4, 256, 0, stream>>>(keep, attn, idx_i, idx_j,
                                                 node_rep, agg, c0, c1);
    final_mfma_kernel<<<(c1 - c0 + 63)/64, 256, 0, stream>>>(node_rep, agg,
                                                 WsH, WsL, bstep, out_rep, c0, c1);
  }
}